// Round 9
// baseline (632.172 us; speedup 1.0000x reference)
//
#include <hip/hip_runtime.h>

#define NN 50000
#define NE 800000
#define DIM 64
#define TL 4
#define ET 3
#define MH 6
#define NBKT 3
#define NB (NN * NBKT)                  // 150000
#define SCAN_BLK ((NB + 1023) / 1024)   // 147
#define LSTRIDE 257                     // 257 % 32 == 1 -> conflict-free lane stride

// ---------------- CSR build: 3 type buckets per node, hop packed in entry ----------------

static __global__ void k_hist3(const int* __restrict__ dst, const int* __restrict__ typ,
                               int* __restrict__ counts) {
    int e = blockIdx.x * blockDim.x + threadIdx.x;
    if (e >= NE) return;
    atomicAdd(&counts[dst[e] * NBKT + typ[e]], 1);
}

static __global__ void k_scanA(const int* __restrict__ counts, int* __restrict__ rs,
                               int* __restrict__ bsum) {
    __shared__ int sm[1024];
    int idx = blockIdx.x * 1024 + threadIdx.x;
    int v = (idx < NB) ? counts[idx] : 0;
    sm[threadIdx.x] = v;
    __syncthreads();
    for (int off = 1; off < 1024; off <<= 1) {
        int t = (threadIdx.x >= off) ? sm[threadIdx.x - off] : 0;
        __syncthreads();
        sm[threadIdx.x] += t;
        __syncthreads();
    }
    if (idx < NB) rs[idx] = sm[threadIdx.x] - v;   // exclusive within block
    if (threadIdx.x == 1023) bsum[blockIdx.x] = sm[1023];
}

static __global__ void k_scanB(const int* __restrict__ bsum, int* __restrict__ bexcl,
                               int* __restrict__ rs) {
    __shared__ int sm[512];
    int tid = threadIdx.x;
    int v = (tid < SCAN_BLK) ? bsum[tid] : 0;
    sm[tid] = v;
    __syncthreads();
    for (int off = 1; off < 512; off <<= 1) {
        int t = (tid >= off) ? sm[tid - off] : 0;
        __syncthreads();
        sm[tid] += t;
        __syncthreads();
    }
    if (tid < SCAN_BLK) bexcl[tid] = sm[tid] - v;
    if (tid == 511) rs[NB] = sm[511];              // grand total
}

static __global__ void k_scanC(int* __restrict__ rs, int* __restrict__ cursor,
                               const int* __restrict__ bexcl) {
    int idx = blockIdx.x * 1024 + threadIdx.x;
    if (idx >= NB) return;
    int r = rs[idx] + bexcl[blockIdx.x];
    rs[idx] = r;
    cursor[idx] = r;
}

static __global__ void k_scatter3(const int* __restrict__ src, const int* __restrict__ dst,
                                  const int* __restrict__ typ, const int* __restrict__ hop,
                                  int* __restrict__ cursor, unsigned int* __restrict__ src_s) {
    int e = blockIdx.x * blockDim.x + threadIdx.x;
    if (e >= NE) return;
    int slot = atomicAdd(&cursor[dst[e] * NBKT + typ[e]], 1);
    src_s[slot] = (unsigned int)src[e] | ((unsigned int)hop[e] << 16);
}

// ---------------- Fused layer: agg (8 nodes/wave -> LDS) + matmul (8 cols/wave) ----------
// Phase 1 = R8 k_agg body, A-rows to LDS instead of global aAll.
// Phase 2 = R6 k_mm body, A from LDS, W via wave-uniform scalar loads.

template <int T>
static __global__ __launch_bounds__(512, 4) void k_fused(
        const int* __restrict__ rs, const unsigned int* __restrict__ src_s,
        const float* __restrict__ xt,
        const float* __restrict__ nu_edge, const float* __restrict__ nu_kt,
        const float* __restrict__ gp2, const float* __restrict__ gp3,
        const float* __restrict__ gp4,
        float* __restrict__ g2, float* __restrict__ g3, float* __restrict__ g4,
        const float* __restrict__ W_edge, const float* __restrict__ b_edge,
        const float* __restrict__ W_t, const float* __restrict__ b_t,
        float* __restrict__ xout) {
    __shared__ float Asm[64 * LSTRIDE];
    const int tid = threadIdx.x;
    const int w = __builtin_amdgcn_readfirstlane(tid >> 6);   // wave id 0..7
    const int lane = tid & 63;
    const int node0 = blockIdx.x * 64;

    const float nu0 = nu_edge[0 * TL + T], nu1 = nu_edge[1 * TL + T],
                nu2 = nu_edge[2 * TL + T];
    const float nk2 = (T >= 1) ? nu_kt[T * MH + 2] : 0.f;
    const float nk3 = (T >= 2) ? nu_kt[T * MH + 3] : 0.f;
    const float nk4 = (T >= 3) ? nu_kt[T * MH + 4] : 0.f;

    // ---------- phase 1: aggregation, wave w handles nodes [8w, 8w+8) ----------
    for (int j = 0; j < 8; ++j) {
        const int node = node0 + w * 8 + j;
        float* __restrict__ lrow = &Asm[(w * 8 + j) * LSTRIDE];
        if (node < NN) {
            const size_t po = (size_t)node * DIM + lane;
            float hp = 0.f;
            if (T >= 1) {
                hp = nk2 * gp2[po];
                if (T >= 2) hp = fmaf(nk3, gp3[po], hp);
                if (T >= 3) hp = fmaf(nk4, gp4[po], hp);
            }
            int ro = 0;
            if (lane < 4) ro = rs[node * NBKT + lane];
            const int b0 = __builtin_amdgcn_readlane(ro, 0);
            const int b1 = __builtin_amdgcn_readlane(ro, 1);
            const int b2 = __builtin_amdgcn_readlane(ro, 2);
            const int b3 = __builtin_amdgcn_readlane(ro, 3);
            const int nt = b3 - b0, t1 = b1 - b0, t2 = b2 - b0;

            float s0 = 0.f, s1 = 0.f, s2 = 0.f;
            float h2 = 0.f, h3 = 0.f, h4 = 0.f;

            if (nt <= 64) {
                int sv = (lane < nt) ? (int)src_s[b0 + lane] : 0;
#pragma unroll 4
                for (int i = 0; i < nt; ++i) {
                    unsigned int sp = (unsigned int)__builtin_amdgcn_readlane(sv, i);
                    int srcn = (int)(sp & 0xFFFFu);
                    int hop = (int)(sp >> 16);
                    float v = xt[(size_t)srcn * DIM + lane];
                    s0 = fmaf((i < t1) ? 1.f : 0.f, v, s0);
                    s1 = fmaf((i >= t1 && i < t2) ? 1.f : 0.f, v, s1);
                    s2 = fmaf((i >= t2) ? 1.f : 0.f, v, s2);
                    if (T <= 2) h2 = fmaf((hop == 2) ? 1.f : 0.f, v, h2);
                    if (T <= 1) h3 = fmaf((hop == 3) ? 1.f : 0.f, v, h3);
                    if (T == 0) h4 = fmaf((hop == 4) ? 1.f : 0.f, v, h4);
                }
            } else {
                for (int i = 0; i < nt; ++i) {
                    unsigned int sp = src_s[b0 + i];       // uniform addr, broadcast
                    int srcn = (int)(sp & 0xFFFFu);
                    int hop = (int)(sp >> 16);
                    float v = xt[(size_t)srcn * DIM + lane];
                    s0 = fmaf((i < t1) ? 1.f : 0.f, v, s0);
                    s1 = fmaf((i >= t1 && i < t2) ? 1.f : 0.f, v, s1);
                    s2 = fmaf((i >= t2) ? 1.f : 0.f, v, s2);
                    if (T <= 2) h2 = fmaf((hop == 2) ? 1.f : 0.f, v, h2);
                    if (T <= 1) h3 = fmaf((hop == 3) ? 1.f : 0.f, v, h3);
                    if (T == 0) h4 = fmaf((hop == 4) ? 1.f : 0.f, v, h4);
                }
            }

            lrow[0 * DIM + lane] = nu0 * s0;
            lrow[1 * DIM + lane] = nu1 * s1;
            lrow[2 * DIM + lane] = nu2 * s2;
            lrow[3 * DIM + lane] = hp;
            if (T <= 2) g2[po] = h2;
            if (T <= 1) g3[po] = h3;
            if (T == 0) g4[po] = h4;
        } else {
            lrow[0 * DIM + lane] = 0.f;
            lrow[1 * DIM + lane] = 0.f;
            lrow[2 * DIM + lane] = 0.f;
            lrow[3 * DIM + lane] = 0.f;
        }
    }
    __syncthreads();

    // ---------- phase 2: matmul, wave w -> cols [8w, 8w+8), lane = node ----------
    const int c0 = w * 8;
    float acc[8];
#pragma unroll
    for (int c = 0; c < 8; ++c) {
        float b = nu0 * b_edge[(0 * TL + T) * DIM + c0 + c]
                + nu1 * b_edge[(1 * TL + T) * DIM + c0 + c]
                + nu2 * b_edge[(2 * TL + T) * DIM + c0 + c];
        if (T >= 1) b = fmaf(nk2 + nk3 + nk4, b_t[T * DIM + c0 + c], b);
        acc[c] = b;
    }

    constexpr int NM = (T >= 1) ? 4 : 3;
#pragma unroll
    for (int m = 0; m < NM; ++m) {
        const float* __restrict__ W = (m == 3) ? (W_t + (size_t)T * DIM * DIM)
                                               : (W_edge + (size_t)(m * TL + T) * DIM * DIM);
        const float* __restrict__ lrow = &Asm[lane * LSTRIDE + m * DIM];
#pragma unroll 4
        for (int dg = 0; dg < 16; ++dg) {
            float a0v = lrow[dg * 4 + 0];
            float a1v = lrow[dg * 4 + 1];
            float a2v = lrow[dg * 4 + 2];
            float a3v = lrow[dg * 4 + 3];
#pragma unroll
            for (int jd = 0; jd < 4; ++jd) {
                const float* __restrict__ Wr = W + (dg * 4 + jd) * DIM + c0;  // wave-uniform
                float a = (jd == 0) ? a0v : (jd == 1) ? a1v : (jd == 2) ? a2v : a3v;
#pragma unroll
                for (int c = 0; c < 8; ++c)
                    acc[c] = fmaf(a, Wr[c], acc[c]);   // s_load W + v_fmac
            }
        }
    }

    const int node = node0 + lane;
    if (node < NN) {
        const float4* __restrict__ X4 = (const float4*)(xt + (size_t)node * DIM + c0);
        float4* __restrict__ O4 = (float4*)(xout + (size_t)node * DIM + c0);
#pragma unroll
        for (int q = 0; q < 2; ++q) {
            float4 xv = X4[q];
            float4 ov;
            ov.x = xv.x + fmaxf(acc[q * 4 + 0], 0.f);
            ov.y = xv.y + fmaxf(acc[q * 4 + 1], 0.f);
            ov.z = xv.z + fmaxf(acc[q * 4 + 2], 0.f);
            ov.w = xv.w + fmaxf(acc[q * 4 + 3], 0.f);
            O4[q] = ov;
        }
    }
}

// ---------------- Host ----------------

extern "C" void kernel_launch(void* const* d_in, const int* in_sizes, int n_in,
                              void* d_out, int out_size, void* d_ws, size_t ws_size,
                              hipStream_t stream) {
    const float* x       = (const float*)d_in[0];
    const float* W_edge  = (const float*)d_in[1];
    const float* b_edge  = (const float*)d_in[2];
    const float* nu_edge = (const float*)d_in[3];
    const float* W_t     = (const float*)d_in[4];
    const float* b_t     = (const float*)d_in[5];
    const float* nu_kt   = (const float*)d_in[6];
    const int* esrc = (const int*)d_in[7];
    const int* edst = (const int*)d_in[8];
    const int* ehop = (const int*)d_in[9];
    const int* etyp = (const int*)d_in[10];
    float* out = (float*)d_out;

    char* ws = (char*)d_ws;
    size_t off = 0;
    auto alloc = [&](size_t bytes) {
        void* p = ws + off;
        off = (off + bytes + 255) & ~(size_t)255;
        return p;
    };
    const size_t PL = (size_t)NN * DIM * 4;          // one feature plane
    int* counts = (int*)alloc((size_t)NB * 4);
    int* rs     = (int*)alloc(((size_t)NB + 1) * 4);
    int* cursor = (int*)alloc((size_t)NB * 4);
    int* bsum   = (int*)alloc(1024 * 4);
    int* bexcl  = (int*)alloc(1024 * 4);
    unsigned int* src_s = (unsigned int*)alloc((size_t)NE * 4);
    float* hA   = (float*)alloc(PL);                 // ping-pong layer outputs
    float* hB   = (float*)alloc(PL);
    float* G2A  = (float*)alloc(PL);                 // rolling hop-sum planes
    float* G2B  = (float*)alloc(PL);
    float* G3A  = (float*)alloc(PL);
    float* G3B  = (float*)alloc(PL);
    float* G4   = (float*)alloc(PL);
    (void)ws_size; (void)in_sizes; (void)n_in; (void)out_size;

    // CSR build (graph static across layers)
    hipMemsetAsync(counts, 0, (size_t)NB * 4, stream);
    k_hist3<<<(NE + 255) / 256, 256, 0, stream>>>(edst, etyp, counts);
    k_scanA<<<SCAN_BLK, 1024, 0, stream>>>(counts, rs, bsum);
    k_scanB<<<1, 512, 0, stream>>>(bsum, bexcl, rs);
    k_scanC<<<SCAN_BLK, 1024, 0, stream>>>(rs, cursor, bexcl);
    k_scatter3<<<(NE + 255) / 256, 256, 0, stream>>>(esrc, edst, etyp, ehop, cursor, src_s);

    const int gf = (NN + 63) / 64;   // 782 fused blocks, 64-node tile each

    // t = 0: write G2[0],G3[0],G4[0]; no hop row
    k_fused<0><<<gf, 512, 0, stream>>>(rs, src_s, x, nu_edge, nu_kt,
                                       G4, G4, G4, G2A, G3A, G4,
                                       W_edge, b_edge, W_t, b_t, hA);
    // t = 1: write G2[1],G3[1]; hop row = nk2*G2[0]
    k_fused<1><<<gf, 512, 0, stream>>>(rs, src_s, hA, nu_edge, nu_kt,
                                       G2A, G4, G4, G2B, G3B, G4,
                                       W_edge, b_edge, W_t, b_t, hB);
    // t = 2: write G2[2] (->G2A, layer-0 content consumed at t=1);
    //        hop row = nk2*G2[1] + nk3*G3[0]
    k_fused<2><<<gf, 512, 0, stream>>>(rs, src_s, hB, nu_edge, nu_kt,
                                       G2B, G3A, G4, G2A, G3A, G4,
                                       W_edge, b_edge, W_t, b_t, hA);
    // t = 3: no G writes; hop row = nk2*G2[2] + nk3*G3[1] + nk4*G4[0]
    k_fused<3><<<gf, 512, 0, stream>>>(rs, src_s, hA, nu_edge, nu_kt,
                                       G2A, G3B, G4, G2B, G3B, G4,
                                       W_edge, b_edge, W_t, b_t, out);
}

// Round 10
// 563.530 us; speedup vs baseline: 1.1218x; 1.1218x over previous
//
#include <hip/hip_runtime.h>

#define NN 50000
#define NN_PAD 50048                    // 64-aligned, covers last k_mm tile
#define NE 800000
#define DIM 64
#define TL 4
#define ET 3
#define MH 6
#define NBKT 3
#define NB (NN * NBKT)                  // 150000
#define SCAN_BLK ((NB + 1023) / 1024)   // 147

__device__ __forceinline__ unsigned bf16rne(float f) {
    unsigned b = __float_as_uint(f);
    return (b + 0x7FFFu + ((b >> 16) & 1u)) >> 16;
}

// ---------------- CSR build: 3 type buckets per node, hop packed in entry ----------------

static __global__ void k_hist3(const int* __restrict__ dst, const int* __restrict__ typ,
                               int* __restrict__ counts) {
    int e = blockIdx.x * blockDim.x + threadIdx.x;
    if (e >= NE) return;
    atomicAdd(&counts[dst[e] * NBKT + typ[e]], 1);
}

static __global__ void k_scanA(const int* __restrict__ counts, int* __restrict__ rs,
                               int* __restrict__ bsum) {
    __shared__ int sm[1024];
    int idx = blockIdx.x * 1024 + threadIdx.x;
    int v = (idx < NB) ? counts[idx] : 0;
    sm[threadIdx.x] = v;
    __syncthreads();
    for (int off = 1; off < 1024; off <<= 1) {
        int t = (threadIdx.x >= off) ? sm[threadIdx.x - off] : 0;
        __syncthreads();
        sm[threadIdx.x] += t;
        __syncthreads();
    }
    if (idx < NB) rs[idx] = sm[threadIdx.x] - v;   // exclusive within block
    if (threadIdx.x == 1023) bsum[blockIdx.x] = sm[1023];
}

static __global__ void k_scanB(const int* __restrict__ bsum, int* __restrict__ bexcl,
                               int* __restrict__ rs) {
    __shared__ int sm[512];
    int tid = threadIdx.x;
    int v = (tid < SCAN_BLK) ? bsum[tid] : 0;
    sm[tid] = v;
    __syncthreads();
    for (int off = 1; off < 512; off <<= 1) {
        int t = (tid >= off) ? sm[tid - off] : 0;
        __syncthreads();
        sm[tid] += t;
        __syncthreads();
    }
    if (tid < SCAN_BLK) bexcl[tid] = sm[tid] - v;
    if (tid == 511) rs[NB] = sm[511];              // grand total
}

static __global__ void k_scanC(int* __restrict__ rs, int* __restrict__ cursor,
                               const int* __restrict__ bexcl) {
    int idx = blockIdx.x * 1024 + threadIdx.x;
    if (idx >= NB) return;
    int r = rs[idx] + bexcl[blockIdx.x];
    rs[idx] = r;
    cursor[idx] = r;
}

static __global__ void k_scatter3(const int* __restrict__ src, const int* __restrict__ dst,
                                  const int* __restrict__ typ, const int* __restrict__ hop,
                                  int* __restrict__ cursor, unsigned int* __restrict__ src_s) {
    int e = blockIdx.x * blockDim.x + threadIdx.x;
    if (e >= NE) return;
    int slot = atomicAdd(&cursor[dst[e] * NBKT + typ[e]], 1);
    src_s[slot] = (unsigned int)src[e] | ((unsigned int)hop[e] << 16);
}

// ---------------- f32 -> bf16 plane convert (initial x only) ----------------

static __global__ void k_cvt(const float* __restrict__ in, unsigned short* __restrict__ out) {
    int i = blockIdx.x * blockDim.x + threadIdx.x;   // one float4 per thread
    if (i >= NN * DIM / 4) return;
    float4 v = ((const float4*)in)[i];
    uint2 p;
    p.x = bf16rne(v.x) | (bf16rne(v.y) << 16);
    p.y = bf16rne(v.z) | (bf16rne(v.w) << 16);
    ((uint2*)out)[i] = p;
}

// ---------------- Aggregation: one wave per node; bf16 gathers; hop row assembled --------

template <int T>
static __global__ __launch_bounds__(256) void k_agg(
        const int* __restrict__ rs, const unsigned int* __restrict__ src_s,
        const unsigned short* __restrict__ xb,
        const float* __restrict__ nu_edge, const float* __restrict__ nu_kt,
        const float* __restrict__ gp2, const float* __restrict__ gp3,
        const float* __restrict__ gp4,
        float* __restrict__ aAll, float* __restrict__ g2,
        float* __restrict__ g3, float* __restrict__ g4) {
    int g = blockIdx.x * blockDim.x + threadIdx.x;
    int node = g >> 6;
    if (node >= NN) return;
    int lane = g & 63;
    const size_t po = (size_t)node * DIM + lane;

    // hop A-row for this layer's matmul: coalesced, independent of gather loop
    float hp = 0.f;
    if (T >= 1) {
        hp = nu_kt[T * MH + 2] * gp2[po];
        if (T >= 2) hp = fmaf(nu_kt[T * MH + 3], gp3[po], hp);
        if (T >= 3) hp = fmaf(nu_kt[T * MH + 4], gp4[po], hp);
    }

    int ro = 0;
    if (lane < 4) ro = rs[node * NBKT + lane];
    const int b0 = __builtin_amdgcn_readlane(ro, 0);
    const int b1 = __builtin_amdgcn_readlane(ro, 1);
    const int b2 = __builtin_amdgcn_readlane(ro, 2);
    const int b3 = __builtin_amdgcn_readlane(ro, 3);
    const int nt = b3 - b0, t1 = b1 - b0, t2 = b2 - b0;

    float s0 = 0.f, s1 = 0.f, s2 = 0.f;
    float h2 = 0.f, h3 = 0.f, h4 = 0.f;

    if (nt <= 64) {
        int sv = (lane < nt) ? (int)src_s[b0 + lane] : 0;
#pragma unroll 8
        for (int i = 0; i < nt; ++i) {
            unsigned int sp = (unsigned int)__builtin_amdgcn_readlane(sv, i);  // SGPR
            int srcn = (int)(sp & 0xFFFFu);
            int hop = (int)(sp >> 16);
            float v = __uint_as_float((unsigned)xb[(size_t)srcn * DIM + lane] << 16);
            s0 = fmaf((i < t1) ? 1.f : 0.f, v, s0);
            s1 = fmaf((i >= t1 && i < t2) ? 1.f : 0.f, v, s1);
            s2 = fmaf((i >= t2) ? 1.f : 0.f, v, s2);
            if (T <= 2) h2 = fmaf((hop == 2) ? 1.f : 0.f, v, h2);
            if (T <= 1) h3 = fmaf((hop == 3) ? 1.f : 0.f, v, h3);
            if (T == 0) h4 = fmaf((hop == 4) ? 1.f : 0.f, v, h4);
        }
    } else {
#pragma unroll 4
        for (int i = 0; i < nt; ++i) {
            unsigned int sp = src_s[b0 + i];           // uniform address, broadcast
            int srcn = (int)(sp & 0xFFFFu);
            int hop = (int)(sp >> 16);
            float v = __uint_as_float((unsigned)xb[(size_t)srcn * DIM + lane] << 16);
            s0 = fmaf((i < t1) ? 1.f : 0.f, v, s0);
            s1 = fmaf((i >= t1 && i < t2) ? 1.f : 0.f, v, s1);
            s2 = fmaf((i >= t2) ? 1.f : 0.f, v, s2);
            if (T <= 2) h2 = fmaf((hop == 2) ? 1.f : 0.f, v, h2);
            if (T <= 1) h3 = fmaf((hop == 3) ? 1.f : 0.f, v, h3);
            if (T == 0) h4 = fmaf((hop == 4) ? 1.f : 0.f, v, h4);
        }
    }

    float nu0 = nu_edge[0 * TL + T], nu1 = nu_edge[1 * TL + T], nu2 = nu_edge[2 * TL + T];
    aAll[(size_t)0 * NN_PAD * DIM + po] = nu0 * s0;
    aAll[(size_t)1 * NN_PAD * DIM + po] = nu1 * s1;
    aAll[(size_t)2 * NN_PAD * DIM + po] = nu2 * s2;
    if (T >= 1) aAll[(size_t)3 * NN_PAD * DIM + po] = hp;
    if (T <= 2) g2[po] = h2;
    if (T <= 1) g3[po] = h3;
    if (T == 0) g4[po] = h4;
}

// ---------------- Matmul: 512 thr / 64-node tile, 8 waves x 8 cols, W scalar ------------

template <int T>
static __global__ __launch_bounds__(512) void k_mm(
        const float* __restrict__ aAll,
        const float* __restrict__ W_edge, const float* __restrict__ b_edge,
        const float* __restrict__ nu_edge,
        const float* __restrict__ W_t, const float* __restrict__ b_t,
        const float* __restrict__ nu_kt,
        const float* __restrict__ xin, float* __restrict__ xout,
        unsigned short* __restrict__ xbo) {
    const int w = __builtin_amdgcn_readfirstlane(threadIdx.x >> 6);  // uniform wave id 0..7
    const int lane = threadIdx.x & 63;
    const int node = blockIdx.x * 64 + lane;     // lane = node within tile
    const int c0 = w * 8;

    const float nu0 = nu_edge[0 * TL + T], nu1 = nu_edge[1 * TL + T],
                nu2 = nu_edge[2 * TL + T];
    float nsum = 0.f;
    if (T >= 1) {
        nsum = nu_kt[T * MH + 2];
        if (T >= 2) nsum += nu_kt[T * MH + 3];
        if (T >= 3) nsum += nu_kt[T * MH + 4];
    }

    float acc[8];
#pragma unroll
    for (int c = 0; c < 8; ++c) {
        float b = nu0 * b_edge[(0 * TL + T) * DIM + c0 + c]
                + nu1 * b_edge[(1 * TL + T) * DIM + c0 + c]
                + nu2 * b_edge[(2 * TL + T) * DIM + c0 + c];
        if (T >= 1) b = fmaf(nsum, b_t[T * DIM + c0 + c], b);
        acc[c] = b;
    }

    const size_t rowoff = ((size_t)blockIdx.x * 64 + lane) * DIM;
    constexpr int NM = (T >= 1) ? 4 : 3;
#pragma unroll
    for (int m = 0; m < NM; ++m) {
        const float* __restrict__ W = (m == 3) ? (W_t + (size_t)T * DIM * DIM)
                                               : (W_edge + (size_t)(m * TL + T) * DIM * DIM);
        const float4* __restrict__ A4 =
            (const float4*)(aAll + (size_t)m * NN_PAD * DIM + rowoff);
#pragma unroll 4
        for (int dg = 0; dg < 16; ++dg) {
            float4 av = A4[dg];
#pragma unroll
            for (int jd = 0; jd < 4; ++jd) {
                const float* __restrict__ Wr = W + (dg * 4 + jd) * DIM + c0;  // wave-uniform
                float a = (jd == 0) ? av.x : (jd == 1) ? av.y : (jd == 2) ? av.z : av.w;
#pragma unroll
                for (int c = 0; c < 8; ++c)
                    acc[c] = fmaf(a, Wr[c], acc[c]);   // s_load W + v_fmac
            }
        }
    }

    if (node < NN) {
        float o[8];
        const float* __restrict__ X = xin + (size_t)node * DIM + c0;
        const float4* __restrict__ X4 = (const float4*)X;
        float4 xv0 = X4[0], xv1 = X4[1];
        o[0] = xv0.x + fmaxf(acc[0], 0.f);
        o[1] = xv0.y + fmaxf(acc[1], 0.f);
        o[2] = xv0.z + fmaxf(acc[2], 0.f);
        o[3] = xv0.w + fmaxf(acc[3], 0.f);
        o[4] = xv1.x + fmaxf(acc[4], 0.f);
        o[5] = xv1.y + fmaxf(acc[5], 0.f);
        o[6] = xv1.z + fmaxf(acc[6], 0.f);
        o[7] = xv1.w + fmaxf(acc[7], 0.f);
        float4* __restrict__ O4 = (float4*)(xout + (size_t)node * DIM + c0);
        O4[0] = make_float4(o[0], o[1], o[2], o[3]);
        O4[1] = make_float4(o[4], o[5], o[6], o[7]);
        if (xbo) {   // bf16 shadow for next layer's gathers
            uint4 pk;
            pk.x = bf16rne(o[0]) | (bf16rne(o[1]) << 16);
            pk.y = bf16rne(o[2]) | (bf16rne(o[3]) << 16);
            pk.z = bf16rne(o[4]) | (bf16rne(o[5]) << 16);
            pk.w = bf16rne(o[6]) | (bf16rne(o[7]) << 16);
            *(uint4*)(xbo + (size_t)node * DIM + c0) = pk;
        }
    }
}

// ---------------- Host ----------------

extern "C" void kernel_launch(void* const* d_in, const int* in_sizes, int n_in,
                              void* d_out, int out_size, void* d_ws, size_t ws_size,
                              hipStream_t stream) {
    const float* x       = (const float*)d_in[0];
    const float* W_edge  = (const float*)d_in[1];
    const float* b_edge  = (const float*)d_in[2];
    const float* nu_edge = (const float*)d_in[3];
    const float* W_t     = (const float*)d_in[4];
    const float* b_t     = (const float*)d_in[5];
    const float* nu_kt   = (const float*)d_in[6];
    const int* esrc = (const int*)d_in[7];
    const int* edst = (const int*)d_in[8];
    const int* ehop = (const int*)d_in[9];
    const int* etyp = (const int*)d_in[10];
    float* out = (float*)d_out;

    char* ws = (char*)d_ws;
    size_t off = 0;
    auto alloc = [&](size_t bytes) {
        void* p = ws + off;
        off = (off + bytes + 255) & ~(size_t)255;
        return p;
    };
    const size_t PL  = (size_t)NN * DIM * 4;         // f32 feature plane
    const size_t PLB = (size_t)NN * DIM * 2;         // bf16 feature plane
    int* counts = (int*)alloc((size_t)NB * 4);
    int* rs     = (int*)alloc(((size_t)NB + 1) * 4);
    int* cursor = (int*)alloc((size_t)NB * 4);
    int* bsum   = (int*)alloc(1024 * 4);
    int* bexcl  = (int*)alloc(1024 * 4);
    unsigned int* src_s = (unsigned int*)alloc((size_t)NE * 4);
    float* hA   = (float*)alloc(PL);                 // ping-pong layer outputs (f32)
    float* hB   = (float*)alloc(PL);
    unsigned short* xb0 = (unsigned short*)alloc(PLB);   // bf16 shadows
    unsigned short* hAb = (unsigned short*)alloc(PLB);
    unsigned short* hBb = (unsigned short*)alloc(PLB);
    float* aAll = (float*)alloc((size_t)4 * NN_PAD * DIM * 4);  // [4][NN_PAD][64]
    float* G2A  = (float*)alloc(PL);                 // rolling hop-sum planes
    float* G2B  = (float*)alloc(PL);
    float* G3A  = (float*)alloc(PL);
    float* G3B  = (float*)alloc(PL);
    float* G4   = (float*)alloc(PL);
    (void)ws_size; (void)in_sizes; (void)n_in; (void)out_size;

    // CSR build (graph static across layers) + initial bf16 convert
    hipMemsetAsync(counts, 0, (size_t)NB * 4, stream);
    k_hist3<<<(NE + 255) / 256, 256, 0, stream>>>(edst, etyp, counts);
    k_cvt<<<(NN * DIM / 4 + 255) / 256, 256, 0, stream>>>(x, xb0);
    k_scanA<<<SCAN_BLK, 1024, 0, stream>>>(counts, rs, bsum);
    k_scanB<<<1, 512, 0, stream>>>(bsum, bexcl, rs);
    k_scanC<<<SCAN_BLK, 1024, 0, stream>>>(rs, cursor, bexcl);
    k_scatter3<<<(NE + 255) / 256, 256, 0, stream>>>(esrc, edst, etyp, ehop, cursor, src_s);

    const int ga = (NN * DIM + 255) / 256;   // one wave per node
    const int gm = NN_PAD / 64;              // 782 blocks, 64-node tile, 512 thr

    // t = 0: write G2[0],G3[0],G4[0]; no hop row
    k_agg<0><<<ga, 256, 0, stream>>>(rs, src_s, xb0, nu_edge, nu_kt,
                                     G4, G4, G4, aAll, G2A, G3A, G4);
    k_mm<0><<<gm, 512, 0, stream>>>(aAll, W_edge, b_edge, nu_edge, W_t, b_t, nu_kt,
                                    x, hA, hAb);
    // t = 1: write G2[1],G3[1]; hop row = nk2*G2[0]
    k_agg<1><<<ga, 256, 0, stream>>>(rs, src_s, hAb, nu_edge, nu_kt,
                                     G2A, G4, G4, aAll, G2B, G3B, G4);
    k_mm<1><<<gm, 512, 0, stream>>>(aAll, W_edge, b_edge, nu_edge, W_t, b_t, nu_kt,
                                    hA, hB, hBb);
    // t = 2: write G2[2] (->G2A, layer-0 content consumed at t=1);
    //        hop row = nk2*G2[1] + nk3*G3[0]
    k_agg<2><<<ga, 256, 0, stream>>>(rs, src_s, hBb, nu_edge, nu_kt,
                                     G2B, G3A, G4, aAll, G2A, G3A, G4);
    k_mm<2><<<gm, 512, 0, stream>>>(aAll, W_edge, b_edge, nu_edge, W_t, b_t, nu_kt,
                                    hB, hA, hAb);
    // t = 3: no G writes; hop row = nk2*G2[2] + nk3*G3[1] + nk4*G4[0]
    k_agg<3><<<ga, 256, 0, stream>>>(rs, src_s, hAb, nu_edge, nu_kt,
                                     G2A, G3B, G4, aAll, G2B, G3B, G4);
    k_mm<3><<<gm, 512, 0, stream>>>(aAll, W_edge, b_edge, nu_edge, W_t, b_t, nu_kt,
                                    hA, out, (unsigned short*)nullptr);
}

// Round 11
// 464.599 us; speedup vs baseline: 1.3607x; 1.2129x over previous
//
#include <hip/hip_runtime.h>

#define NN 50000
#define NN_PAD 50048                    // 64-aligned, covers last k_mm tile
#define NE 800000
#define DIM 64
#define TL 4
#define ET 3
#define MH 6
#define NBKT 3
#define NB (NN * NBKT)                  // 150000
#define SCAN_BLK ((NB + 1023) / 1024)   // 147

__device__ __forceinline__ unsigned bf16rne(float f) {
    unsigned b = __float_as_uint(f);
    return (b + 0x7FFFu + ((b >> 16) & 1u)) >> 16;
}

// ---------------- CSR build: 3 type buckets per node, hop packed in entry ----------------

static __global__ void k_hist3(const int* __restrict__ dst, const int* __restrict__ typ,
                               int* __restrict__ counts) {
    int e = blockIdx.x * blockDim.x + threadIdx.x;
    if (e >= NE) return;
    atomicAdd(&counts[dst[e] * NBKT + typ[e]], 1);
}

static __global__ void k_scanA(const int* __restrict__ counts, int* __restrict__ rs,
                               int* __restrict__ bsum) {
    __shared__ int sm[1024];
    int idx = blockIdx.x * 1024 + threadIdx.x;
    int v = (idx < NB) ? counts[idx] : 0;
    sm[threadIdx.x] = v;
    __syncthreads();
    for (int off = 1; off < 1024; off <<= 1) {
        int t = (threadIdx.x >= off) ? sm[threadIdx.x - off] : 0;
        __syncthreads();
        sm[threadIdx.x] += t;
        __syncthreads();
    }
    if (idx < NB) rs[idx] = sm[threadIdx.x] - v;   // exclusive within block
    if (threadIdx.x == 1023) bsum[blockIdx.x] = sm[1023];
}

static __global__ void k_scanB(const int* __restrict__ bsum, int* __restrict__ bexcl,
                               int* __restrict__ rs) {
    __shared__ int sm[512];
    int tid = threadIdx.x;
    int v = (tid < SCAN_BLK) ? bsum[tid] : 0;
    sm[tid] = v;
    __syncthreads();
    for (int off = 1; off < 512; off <<= 1) {
        int t = (tid >= off) ? sm[tid - off] : 0;
        __syncthreads();
        sm[tid] += t;
        __syncthreads();
    }
    if (tid < SCAN_BLK) bexcl[tid] = sm[tid] - v;
    if (tid == 511) rs[NB] = sm[511];              // grand total
}

static __global__ void k_scanC(int* __restrict__ rs, int* __restrict__ cursor,
                               const int* __restrict__ bexcl) {
    int idx = blockIdx.x * 1024 + threadIdx.x;
    if (idx >= NB) return;
    int r = rs[idx] + bexcl[blockIdx.x];
    rs[idx] = r;
    cursor[idx] = r;
}

static __global__ void k_scatter3(const int* __restrict__ src, const int* __restrict__ dst,
                                  const int* __restrict__ typ, const int* __restrict__ hop,
                                  int* __restrict__ cursor, unsigned int* __restrict__ src_s) {
    int e = blockIdx.x * blockDim.x + threadIdx.x;
    if (e >= NE) return;
    int slot = atomicAdd(&cursor[dst[e] * NBKT + typ[e]], 1);
    src_s[slot] = (unsigned int)src[e] | ((unsigned int)hop[e] << 16);
}

// ---------------- f32 -> bf16 plane convert (initial x only) ----------------

static __global__ void k_cvt(const float* __restrict__ in, unsigned short* __restrict__ out) {
    int i = blockIdx.x * blockDim.x + threadIdx.x;   // one float4 per thread
    if (i >= NN * DIM / 4) return;
    float4 v = ((const float4*)in)[i];
    uint2 p;
    p.x = bf16rne(v.x) | (bf16rne(v.y) << 16);
    p.y = bf16rne(v.z) | (bf16rne(v.w) << 16);
    ((uint2*)out)[i] = p;
}

// ---------------- Aggregation: one wave per node; bf16 gathers; hop row assembled --------

template <int T>
static __global__ __launch_bounds__(256) void k_agg(
        const int* __restrict__ rs, const unsigned int* __restrict__ src_s,
        const unsigned short* __restrict__ xb,
        const float* __restrict__ nu_edge, const float* __restrict__ nu_kt,
        const float* __restrict__ gp2, const float* __restrict__ gp3,
        const float* __restrict__ gp4,
        float* __restrict__ aAll, float* __restrict__ g2,
        float* __restrict__ g3, float* __restrict__ g4) {
    int g = blockIdx.x * blockDim.x + threadIdx.x;
    int node = g >> 6;
    if (node >= NN) return;
    int lane = g & 63;
    const size_t po = (size_t)node * DIM + lane;

    // hop A-row for this layer's matmul: coalesced, independent of gather loop
    float hp = 0.f;
    if (T >= 1) {
        hp = nu_kt[T * MH + 2] * gp2[po];
        if (T >= 2) hp = fmaf(nu_kt[T * MH + 3], gp3[po], hp);
        if (T >= 3) hp = fmaf(nu_kt[T * MH + 4], gp4[po], hp);
    }

    int ro = 0;
    if (lane < 4) ro = rs[node * NBKT + lane];
    const int b0 = __builtin_amdgcn_readlane(ro, 0);
    const int b1 = __builtin_amdgcn_readlane(ro, 1);
    const int b2 = __builtin_amdgcn_readlane(ro, 2);
    const int b3 = __builtin_amdgcn_readlane(ro, 3);
    const int nt = b3 - b0, t1 = b1 - b0, t2 = b2 - b0;

    float s0 = 0.f, s1 = 0.f, s2 = 0.f;
    float h2 = 0.f, h3 = 0.f, h4 = 0.f;

    if (nt <= 64) {
        int sv = (lane < nt) ? (int)src_s[b0 + lane] : 0;
#pragma unroll 8
        for (int i = 0; i < nt; ++i) {
            unsigned int sp = (unsigned int)__builtin_amdgcn_readlane(sv, i);  // SGPR
            int srcn = (int)(sp & 0xFFFFu);
            int hop = (int)(sp >> 16);
            float v = __uint_as_float((unsigned)xb[(size_t)srcn * DIM + lane] << 16);
            s0 = fmaf((i < t1) ? 1.f : 0.f, v, s0);
            s1 = fmaf((i >= t1 && i < t2) ? 1.f : 0.f, v, s1);
            s2 = fmaf((i >= t2) ? 1.f : 0.f, v, s2);
            if (T <= 2) h2 = fmaf((hop == 2) ? 1.f : 0.f, v, h2);
            if (T <= 1) h3 = fmaf((hop == 3) ? 1.f : 0.f, v, h3);
            if (T == 0) h4 = fmaf((hop == 4) ? 1.f : 0.f, v, h4);
        }
    } else {
#pragma unroll 4
        for (int i = 0; i < nt; ++i) {
            unsigned int sp = src_s[b0 + i];           // uniform address, broadcast
            int srcn = (int)(sp & 0xFFFFu);
            int hop = (int)(sp >> 16);
            float v = __uint_as_float((unsigned)xb[(size_t)srcn * DIM + lane] << 16);
            s0 = fmaf((i < t1) ? 1.f : 0.f, v, s0);
            s1 = fmaf((i >= t1 && i < t2) ? 1.f : 0.f, v, s1);
            s2 = fmaf((i >= t2) ? 1.f : 0.f, v, s2);
            if (T <= 2) h2 = fmaf((hop == 2) ? 1.f : 0.f, v, h2);
            if (T <= 1) h3 = fmaf((hop == 3) ? 1.f : 0.f, v, h3);
            if (T == 0) h4 = fmaf((hop == 4) ? 1.f : 0.f, v, h4);
        }
    }

    float nu0 = nu_edge[0 * TL + T], nu1 = nu_edge[1 * TL + T], nu2 = nu_edge[2 * TL + T];
    aAll[(size_t)0 * NN_PAD * DIM + po] = nu0 * s0;
    aAll[(size_t)1 * NN_PAD * DIM + po] = nu1 * s1;
    aAll[(size_t)2 * NN_PAD * DIM + po] = nu2 * s2;
    if (T >= 1) aAll[(size_t)3 * NN_PAD * DIM + po] = hp;
    if (T <= 2) g2[po] = h2;
    if (T <= 1) g3[po] = h3;
    if (T == 0) g4[po] = h4;
}

// ---------------- Matmul (R8-proven shape): 256 thr, 4 waves x 16 cols, lane = node ------

template <int T>
static __global__ __launch_bounds__(256) void k_mm(
        const float* __restrict__ aAll,
        const float* __restrict__ W_edge, const float* __restrict__ b_edge,
        const float* __restrict__ nu_edge,
        const float* __restrict__ W_t, const float* __restrict__ b_t,
        const float* __restrict__ nu_kt,
        const float* __restrict__ xin, float* __restrict__ xout,
        unsigned short* __restrict__ xbo) {
    const int w = __builtin_amdgcn_readfirstlane(threadIdx.x >> 6);  // uniform wave id
    const int lane = threadIdx.x & 63;
    const int node = blockIdx.x * 64 + lane;     // lane = node within tile
    const int c0 = w * 16;

    const float nu0 = nu_edge[0 * TL + T], nu1 = nu_edge[1 * TL + T],
                nu2 = nu_edge[2 * TL + T];
    float nsum = 0.f;
    if (T >= 1) {
        nsum = nu_kt[T * MH + 2];
        if (T >= 2) nsum += nu_kt[T * MH + 3];
        if (T >= 3) nsum += nu_kt[T * MH + 4];
    }

    float acc[16];
#pragma unroll
    for (int c = 0; c < 16; ++c) {
        float b = nu0 * b_edge[(0 * TL + T) * DIM + c0 + c]
                + nu1 * b_edge[(1 * TL + T) * DIM + c0 + c]
                + nu2 * b_edge[(2 * TL + T) * DIM + c0 + c];
        if (T >= 1) b = fmaf(nsum, b_t[T * DIM + c0 + c], b);
        acc[c] = b;
    }

    const size_t rowoff = ((size_t)blockIdx.x * 64 + lane) * DIM;
    constexpr int NM = (T >= 1) ? 4 : 3;
#pragma unroll
    for (int m = 0; m < NM; ++m) {
        const float* __restrict__ W = (m == 3) ? (W_t + (size_t)T * DIM * DIM)
                                               : (W_edge + (size_t)(m * TL + T) * DIM * DIM);
        const float4* __restrict__ A4 =
            (const float4*)(aAll + (size_t)m * NN_PAD * DIM + rowoff);
#pragma unroll 4
        for (int dg = 0; dg < 16; ++dg) {
            float4 av = A4[dg];
#pragma unroll
            for (int jd = 0; jd < 4; ++jd) {
                const float* __restrict__ Wr = W + (dg * 4 + jd) * DIM + c0;  // wave-uniform
                float a = (jd == 0) ? av.x : (jd == 1) ? av.y : (jd == 2) ? av.z : av.w;
#pragma unroll
                for (int c = 0; c < 16; ++c)
                    acc[c] = fmaf(a, Wr[c], acc[c]);   // s_load W + v_fmac
            }
        }
    }

    if (node < NN) {
        const float4* __restrict__ X4 = (const float4*)(xin + (size_t)node * DIM + c0);
        float4* __restrict__ O4 = (float4*)(xout + (size_t)node * DIM + c0);
        float o[16];
#pragma unroll
        for (int q = 0; q < 4; ++q) {
            float4 xv = X4[q];
            o[q * 4 + 0] = xv.x + fmaxf(acc[q * 4 + 0], 0.f);
            o[q * 4 + 1] = xv.y + fmaxf(acc[q * 4 + 1], 0.f);
            o[q * 4 + 2] = xv.z + fmaxf(acc[q * 4 + 2], 0.f);
            o[q * 4 + 3] = xv.w + fmaxf(acc[q * 4 + 3], 0.f);
            O4[q] = make_float4(o[q * 4 + 0], o[q * 4 + 1], o[q * 4 + 2], o[q * 4 + 3]);
        }
        if (xbo) {   // bf16 shadow for next layer's gathers
            uint4 pk0, pk1;
            pk0.x = bf16rne(o[0])  | (bf16rne(o[1])  << 16);
            pk0.y = bf16rne(o[2])  | (bf16rne(o[3])  << 16);
            pk0.z = bf16rne(o[4])  | (bf16rne(o[5])  << 16);
            pk0.w = bf16rne(o[6])  | (bf16rne(o[7])  << 16);
            pk1.x = bf16rne(o[8])  | (bf16rne(o[9])  << 16);
            pk1.y = bf16rne(o[10]) | (bf16rne(o[11]) << 16);
            pk1.z = bf16rne(o[12]) | (bf16rne(o[13]) << 16);
            pk1.w = bf16rne(o[14]) | (bf16rne(o[15]) << 16);
            uint4* B4 = (uint4*)(xbo + (size_t)node * DIM + c0);
            B4[0] = pk0;
            B4[1] = pk1;
        }
    }
}

// ---------------- Host ----------------

extern "C" void kernel_launch(void* const* d_in, const int* in_sizes, int n_in,
                              void* d_out, int out_size, void* d_ws, size_t ws_size,
                              hipStream_t stream) {
    const float* x       = (const float*)d_in[0];
    const float* W_edge  = (const float*)d_in[1];
    const float* b_edge  = (const float*)d_in[2];
    const float* nu_edge = (const float*)d_in[3];
    const float* W_t     = (const float*)d_in[4];
    const float* b_t     = (const float*)d_in[5];
    const float* nu_kt   = (const float*)d_in[6];
    const int* esrc = (const int*)d_in[7];
    const int* edst = (const int*)d_in[8];
    const int* ehop = (const int*)d_in[9];
    const int* etyp = (const int*)d_in[10];
    float* out = (float*)d_out;

    char* ws = (char*)d_ws;
    size_t off = 0;
    auto alloc = [&](size_t bytes) {
        void* p = ws + off;
        off = (off + bytes + 255) & ~(size_t)255;
        return p;
    };
    const size_t PL  = (size_t)NN * DIM * 4;         // f32 feature plane
    const size_t PLB = (size_t)NN * DIM * 2;         // bf16 feature plane
    int* counts = (int*)alloc((size_t)NB * 4);
    int* rs     = (int*)alloc(((size_t)NB + 1) * 4);
    int* cursor = (int*)alloc((size_t)NB * 4);
    int* bsum   = (int*)alloc(1024 * 4);
    int* bexcl  = (int*)alloc(1024 * 4);
    unsigned int* src_s = (unsigned int*)alloc((size_t)NE * 4);
    float* hA   = (float*)alloc(PL);                 // ping-pong layer outputs (f32)
    float* hB   = (float*)alloc(PL);
    unsigned short* xb0 = (unsigned short*)alloc(PLB);   // bf16 shadows
    unsigned short* hAb = (unsigned short*)alloc(PLB);
    unsigned short* hBb = (unsigned short*)alloc(PLB);
    float* aAll = (float*)alloc((size_t)4 * NN_PAD * DIM * 4);  // [4][NN_PAD][64]
    float* G2A  = (float*)alloc(PL);                 // rolling hop-sum planes
    float* G2B  = (float*)alloc(PL);
    float* G3A  = (float*)alloc(PL);
    float* G3B  = (float*)alloc(PL);
    float* G4   = (float*)alloc(PL);
    (void)ws_size; (void)in_sizes; (void)n_in; (void)out_size;

    // CSR build (graph static across layers) + initial bf16 convert
    hipMemsetAsync(counts, 0, (size_t)NB * 4, stream);
    k_hist3<<<(NE + 255) / 256, 256, 0, stream>>>(edst, etyp, counts);
    k_cvt<<<(NN * DIM / 4 + 255) / 256, 256, 0, stream>>>(x, xb0);
    k_scanA<<<SCAN_BLK, 1024, 0, stream>>>(counts, rs, bsum);
    k_scanB<<<1, 512, 0, stream>>>(bsum, bexcl, rs);
    k_scanC<<<SCAN_BLK, 1024, 0, stream>>>(rs, cursor, bexcl);
    k_scatter3<<<(NE + 255) / 256, 256, 0, stream>>>(esrc, edst, etyp, ehop, cursor, src_s);

    const int ga = (NN * DIM + 255) / 256;   // one wave per node
    const int gm = NN_PAD / 64;              // 782 blocks, 64-node tile, 256 thr

    // t = 0: write G2[0],G3[0],G4[0]; no hop row
    k_agg<0><<<ga, 256, 0, stream>>>(rs, src_s, xb0, nu_edge, nu_kt,
                                     G4, G4, G4, aAll, G2A, G3A, G4);
    k_mm<0><<<gm, 256, 0, stream>>>(aAll, W_edge, b_edge, nu_edge, W_t, b_t, nu_kt,
                                    x, hA, hAb);
    // t = 1: write G2[1],G3[1]; hop row = nk2*G2[0]
    k_agg<1><<<ga, 256, 0, stream>>>(rs, src_s, hAb, nu_edge, nu_kt,
                                     G2A, G4, G4, aAll, G2B, G3B, G4);
    k_mm<1><<<gm, 256, 0, stream>>>(aAll, W_edge, b_edge, nu_edge, W_t, b_t, nu_kt,
                                    hA, hB, hBb);
    // t = 2: write G2[2] (->G2A, layer-0 content consumed at t=1);
    //        hop row = nk2*G2[1] + nk3*G3[0]
    k_agg<2><<<ga, 256, 0, stream>>>(rs, src_s, hBb, nu_edge, nu_kt,
                                     G2B, G3A, G4, aAll, G2A, G3A, G4);
    k_mm<2><<<gm, 256, 0, stream>>>(aAll, W_edge, b_edge, nu_edge, W_t, b_t, nu_kt,
                                    hB, hA, hAb);
    // t = 3: no G writes; hop row = nk2*G2[2] + nk3*G3[1] + nk4*G4[0]
    k_agg<3><<<ga, 256, 0, stream>>>(rs, src_s, hAb, nu_edge, nu_kt,
                                     G2A, G3B, G4, aAll, G2B, G3B, G4);
    k_mm<3><<<gm, 256, 0, stream>>>(aAll, W_edge, b_edge, nu_edge, W_t, b_t, nu_kt,
                                    hA, out, (unsigned short*)nullptr);
}

// Round 12
// 438.333 us; speedup vs baseline: 1.4422x; 1.0599x over previous
//
#include <hip/hip_runtime.h>

#define NN 50000
#define NN_PAD 50048                    // 64-aligned, covers last k_mm tile
#define NE 800000
#define DIM 64
#define TL 4
#define ET 3
#define MH 6
#define NBKT 3
#define NB (NN * NBKT)                  // 150000
#define SCAN_BLK ((NB + 1023) / 1024)   // 147

__device__ __forceinline__ unsigned bf16rne(float f) {
    unsigned b = __float_as_uint(f);
    return (b + 0x7FFFu + ((b >> 16) & 1u)) >> 16;
}
__device__ __forceinline__ float bf2f(unsigned short u) {
    return __uint_as_float((unsigned)u << 16);
}

// ---------------- CSR build: 3 type buckets per node, hop packed in entry ----------------

static __global__ void k_hist3(const int* __restrict__ dst, const int* __restrict__ typ,
                               int* __restrict__ counts) {
    int e = blockIdx.x * blockDim.x + threadIdx.x;
    if (e >= NE) return;
    atomicAdd(&counts[dst[e] * NBKT + typ[e]], 1);
}

static __global__ void k_scanA(const int* __restrict__ counts, int* __restrict__ rs,
                               int* __restrict__ bsum) {
    __shared__ int sm[1024];
    int idx = blockIdx.x * 1024 + threadIdx.x;
    int v = (idx < NB) ? counts[idx] : 0;
    sm[threadIdx.x] = v;
    __syncthreads();
    for (int off = 1; off < 1024; off <<= 1) {
        int t = (threadIdx.x >= off) ? sm[threadIdx.x - off] : 0;
        __syncthreads();
        sm[threadIdx.x] += t;
        __syncthreads();
    }
    if (idx < NB) rs[idx] = sm[threadIdx.x] - v;   // exclusive within block
    if (threadIdx.x == 1023) bsum[blockIdx.x] = sm[1023];
}

static __global__ void k_scanB(const int* __restrict__ bsum, int* __restrict__ bexcl,
                               int* __restrict__ rs) {
    __shared__ int sm[512];
    int tid = threadIdx.x;
    int v = (tid < SCAN_BLK) ? bsum[tid] : 0;
    sm[tid] = v;
    __syncthreads();
    for (int off = 1; off < 512; off <<= 1) {
        int t = (tid >= off) ? sm[tid - off] : 0;
        __syncthreads();
        sm[tid] += t;
        __syncthreads();
    }
    if (tid < SCAN_BLK) bexcl[tid] = sm[tid] - v;
    if (tid == 511) rs[NB] = sm[511];              // grand total
}

static __global__ void k_scanC(int* __restrict__ rs, int* __restrict__ cursor,
                               const int* __restrict__ bexcl) {
    int idx = blockIdx.x * 1024 + threadIdx.x;
    if (idx >= NB) return;
    int r = rs[idx] + bexcl[blockIdx.x];
    rs[idx] = r;
    cursor[idx] = r;
}

static __global__ void k_scatter3(const int* __restrict__ src, const int* __restrict__ dst,
                                  const int* __restrict__ typ, const int* __restrict__ hop,
                                  int* __restrict__ cursor, unsigned int* __restrict__ src_s) {
    int e = blockIdx.x * blockDim.x + threadIdx.x;
    if (e >= NE) return;
    int slot = atomicAdd(&cursor[dst[e] * NBKT + typ[e]], 1);
    src_s[slot] = (unsigned int)src[e] | ((unsigned int)hop[e] << 16);
}

// ---------------- f32 -> bf16 plane convert (initial x only) ----------------

static __global__ void k_cvt(const float* __restrict__ in, unsigned short* __restrict__ out) {
    int i = blockIdx.x * blockDim.x + threadIdx.x;   // one float4 per thread
    if (i >= NN * DIM / 4) return;
    float4 v = ((const float4*)in)[i];
    uint2 p;
    p.x = bf16rne(v.x) | (bf16rne(v.y) << 16);
    p.y = bf16rne(v.z) | (bf16rne(v.w) << 16);
    ((uint2*)out)[i] = p;
}

// ---------------- Aggregation: one wave per node; bf16 gathers; bf16 planes out ----------

template <int T>
static __global__ __launch_bounds__(256) void k_agg(
        const int* __restrict__ rs, const unsigned int* __restrict__ src_s,
        const unsigned short* __restrict__ xb,
        const float* __restrict__ nu_edge, const float* __restrict__ nu_kt,
        const unsigned short* __restrict__ gp2, const unsigned short* __restrict__ gp3,
        const unsigned short* __restrict__ gp4,
        unsigned short* __restrict__ aAll, unsigned short* __restrict__ g2,
        unsigned short* __restrict__ g3, unsigned short* __restrict__ g4) {
    int g = blockIdx.x * blockDim.x + threadIdx.x;
    int node = g >> 6;
    if (node >= NN) return;
    int lane = g & 63;
    const size_t po = (size_t)node * DIM + lane;

    // hop A-row for this layer's matmul: coalesced bf16 loads, independent of gather loop
    float hp = 0.f;
    if (T >= 1) {
        hp = nu_kt[T * MH + 2] * bf2f(gp2[po]);
        if (T >= 2) hp = fmaf(nu_kt[T * MH + 3], bf2f(gp3[po]), hp);
        if (T >= 3) hp = fmaf(nu_kt[T * MH + 4], bf2f(gp4[po]), hp);
    }

    int ro = 0;
    if (lane < 4) ro = rs[node * NBKT + lane];
    const int b0 = __builtin_amdgcn_readlane(ro, 0);
    const int b1 = __builtin_amdgcn_readlane(ro, 1);
    const int b2 = __builtin_amdgcn_readlane(ro, 2);
    const int b3 = __builtin_amdgcn_readlane(ro, 3);
    const int nt = b3 - b0, t1 = b1 - b0, t2 = b2 - b0;

    float s0 = 0.f, s1 = 0.f, s2 = 0.f;
    float h2 = 0.f, h3 = 0.f, h4 = 0.f;

    if (nt <= 64) {
        int sv = (lane < nt) ? (int)src_s[b0 + lane] : 0;
#pragma unroll 16
        for (int i = 0; i < nt; ++i) {
            unsigned int sp = (unsigned int)__builtin_amdgcn_readlane(sv, i);  // SGPR
            int srcn = (int)(sp & 0xFFFFu);
            int hop = (int)(sp >> 16);
            float v = bf2f(xb[(size_t)srcn * DIM + lane]);
            s0 = fmaf((i < t1) ? 1.f : 0.f, v, s0);
            s1 = fmaf((i >= t1 && i < t2) ? 1.f : 0.f, v, s1);
            s2 = fmaf((i >= t2) ? 1.f : 0.f, v, s2);
            if (T <= 2) h2 = fmaf((hop == 2) ? 1.f : 0.f, v, h2);
            if (T <= 1) h3 = fmaf((hop == 3) ? 1.f : 0.f, v, h3);
            if (T == 0) h4 = fmaf((hop == 4) ? 1.f : 0.f, v, h4);
        }
    } else {
#pragma unroll 4
        for (int i = 0; i < nt; ++i) {
            unsigned int sp = src_s[b0 + i];           // uniform address, broadcast
            int srcn = (int)(sp & 0xFFFFu);
            int hop = (int)(sp >> 16);
            float v = bf2f(xb[(size_t)srcn * DIM + lane]);
            s0 = fmaf((i < t1) ? 1.f : 0.f, v, s0);
            s1 = fmaf((i >= t1 && i < t2) ? 1.f : 0.f, v, s1);
            s2 = fmaf((i >= t2) ? 1.f : 0.f, v, s2);
            if (T <= 2) h2 = fmaf((hop == 2) ? 1.f : 0.f, v, h2);
            if (T <= 1) h3 = fmaf((hop == 3) ? 1.f : 0.f, v, h3);
            if (T == 0) h4 = fmaf((hop == 4) ? 1.f : 0.f, v, h4);
        }
    }

    float nu0 = nu_edge[0 * TL + T], nu1 = nu_edge[1 * TL + T], nu2 = nu_edge[2 * TL + T];
    aAll[(size_t)0 * NN_PAD * DIM + po] = (unsigned short)bf16rne(nu0 * s0);
    aAll[(size_t)1 * NN_PAD * DIM + po] = (unsigned short)bf16rne(nu1 * s1);
    aAll[(size_t)2 * NN_PAD * DIM + po] = (unsigned short)bf16rne(nu2 * s2);
    if (T >= 1) aAll[(size_t)3 * NN_PAD * DIM + po] = (unsigned short)bf16rne(hp);
    if (T <= 2) g2[po] = (unsigned short)bf16rne(h2);
    if (T <= 1) g3[po] = (unsigned short)bf16rne(h3);
    if (T == 0) g4[po] = (unsigned short)bf16rne(h4);
}

// ---------------- Matmul: 256 thr, 4 waves x 16 cols, lane = node, bf16 A-planes ---------

template <int T>
static __global__ __launch_bounds__(256) void k_mm(
        const unsigned short* __restrict__ aAll,
        const float* __restrict__ W_edge, const float* __restrict__ b_edge,
        const float* __restrict__ nu_edge,
        const float* __restrict__ W_t, const float* __restrict__ b_t,
        const float* __restrict__ nu_kt,
        const float* __restrict__ xin, float* __restrict__ xout,
        unsigned short* __restrict__ xbo) {
    const int w = __builtin_amdgcn_readfirstlane(threadIdx.x >> 6);  // uniform wave id
    const int lane = threadIdx.x & 63;
    const int node = blockIdx.x * 64 + lane;     // lane = node within tile
    const int c0 = w * 16;

    const float nu0 = nu_edge[0 * TL + T], nu1 = nu_edge[1 * TL + T],
                nu2 = nu_edge[2 * TL + T];
    float nsum = 0.f;
    if (T >= 1) {
        nsum = nu_kt[T * MH + 2];
        if (T >= 2) nsum += nu_kt[T * MH + 3];
        if (T >= 3) nsum += nu_kt[T * MH + 4];
    }

    float acc[16];
#pragma unroll
    for (int c = 0; c < 16; ++c) {
        float b = nu0 * b_edge[(0 * TL + T) * DIM + c0 + c]
                + nu1 * b_edge[(1 * TL + T) * DIM + c0 + c]
                + nu2 * b_edge[(2 * TL + T) * DIM + c0 + c];
        if (T >= 1) b = fmaf(nsum, b_t[T * DIM + c0 + c], b);
        acc[c] = b;
    }

    const size_t rowoff = ((size_t)blockIdx.x * 64 + lane) * DIM;
    constexpr int NM = (T >= 1) ? 4 : 3;
#pragma unroll
    for (int m = 0; m < NM; ++m) {
        const float* __restrict__ W = (m == 3) ? (W_t + (size_t)T * DIM * DIM)
                                               : (W_edge + (size_t)(m * TL + T) * DIM * DIM);
        const uint4* __restrict__ A8 =
            (const uint4*)(aAll + (size_t)m * NN_PAD * DIM + rowoff);
#pragma unroll 4
        for (int g8 = 0; g8 < 8; ++g8) {             // 8 bf16 per uint4
            uint4 pk = A8[g8];
            float a[8];
            a[0] = __uint_as_float(pk.x << 16);
            a[1] = __uint_as_float(pk.x & 0xFFFF0000u);
            a[2] = __uint_as_float(pk.y << 16);
            a[3] = __uint_as_float(pk.y & 0xFFFF0000u);
            a[4] = __uint_as_float(pk.z << 16);
            a[5] = __uint_as_float(pk.z & 0xFFFF0000u);
            a[6] = __uint_as_float(pk.w << 16);
            a[7] = __uint_as_float(pk.w & 0xFFFF0000u);
#pragma unroll
            for (int jd = 0; jd < 8; ++jd) {
                const float* __restrict__ Wr = W + (g8 * 8 + jd) * DIM + c0;  // wave-uniform
#pragma unroll
                for (int c = 0; c < 16; ++c)
                    acc[c] = fmaf(a[jd], Wr[c], acc[c]);   // s_load W + v_fmac
            }
        }
    }

    if (node < NN) {
        const float4* __restrict__ X4 = (const float4*)(xin + (size_t)node * DIM + c0);
        float4* __restrict__ O4 = (float4*)(xout + (size_t)node * DIM + c0);
        float o[16];
#pragma unroll
        for (int q = 0; q < 4; ++q) {
            float4 xv = X4[q];
            o[q * 4 + 0] = xv.x + fmaxf(acc[q * 4 + 0], 0.f);
            o[q * 4 + 1] = xv.y + fmaxf(acc[q * 4 + 1], 0.f);
            o[q * 4 + 2] = xv.z + fmaxf(acc[q * 4 + 2], 0.f);
            o[q * 4 + 3] = xv.w + fmaxf(acc[q * 4 + 3], 0.f);
            O4[q] = make_float4(o[q * 4 + 0], o[q * 4 + 1], o[q * 4 + 2], o[q * 4 + 3]);
        }
        if (xbo) {   // bf16 shadow for next layer's gathers
            uint4 pk0, pk1;
            pk0.x = bf16rne(o[0])  | (bf16rne(o[1])  << 16);
            pk0.y = bf16rne(o[2])  | (bf16rne(o[3])  << 16);
            pk0.z = bf16rne(o[4])  | (bf16rne(o[5])  << 16);
            pk0.w = bf16rne(o[6])  | (bf16rne(o[7])  << 16);
            pk1.x = bf16rne(o[8])  | (bf16rne(o[9])  << 16);
            pk1.y = bf16rne(o[10]) | (bf16rne(o[11]) << 16);
            pk1.z = bf16rne(o[12]) | (bf16rne(o[13]) << 16);
            pk1.w = bf16rne(o[14]) | (bf16rne(o[15]) << 16);
            uint4* B4 = (uint4*)(xbo + (size_t)node * DIM + c0);
            B4[0] = pk0;
            B4[1] = pk1;
        }
    }
}

// ---------------- Host ----------------

extern "C" void kernel_launch(void* const* d_in, const int* in_sizes, int n_in,
                              void* d_out, int out_size, void* d_ws, size_t ws_size,
                              hipStream_t stream) {
    const float* x       = (const float*)d_in[0];
    const float* W_edge  = (const float*)d_in[1];
    const float* b_edge  = (const float*)d_in[2];
    const float* nu_edge = (const float*)d_in[3];
    const float* W_t     = (const float*)d_in[4];
    const float* b_t     = (const float*)d_in[5];
    const float* nu_kt   = (const float*)d_in[6];
    const int* esrc = (const int*)d_in[7];
    const int* edst = (const int*)d_in[8];
    const int* ehop = (const int*)d_in[9];
    const int* etyp = (const int*)d_in[10];
    float* out = (float*)d_out;

    char* ws = (char*)d_ws;
    size_t off = 0;
    auto alloc = [&](size_t bytes) {
        void* p = ws + off;
        off = (off + bytes + 255) & ~(size_t)255;
        return p;
    };
    const size_t PL  = (size_t)NN * DIM * 4;         // f32 feature plane
    const size_t PLB = (size_t)NN * DIM * 2;         // bf16 feature plane
    int* counts = (int*)alloc((size_t)NB * 4);
    int* rs     = (int*)alloc(((size_t)NB + 1) * 4);
    int* cursor = (int*)alloc((size_t)NB * 4);
    int* bsum   = (int*)alloc(1024 * 4);
    int* bexcl  = (int*)alloc(1024 * 4);
    unsigned int* src_s = (unsigned int*)alloc((size_t)NE * 4);
    float* hA   = (float*)alloc(PL);                 // ping-pong layer outputs (f32)
    float* hB   = (float*)alloc(PL);
    unsigned short* xb0 = (unsigned short*)alloc(PLB);   // bf16 shadows
    unsigned short* hAb = (unsigned short*)alloc(PLB);
    unsigned short* hBb = (unsigned short*)alloc(PLB);
    unsigned short* aAll = (unsigned short*)alloc((size_t)4 * NN_PAD * DIM * 2);  // bf16 [4][NN_PAD][64]
    unsigned short* G2A  = (unsigned short*)alloc(PLB);  // rolling hop-sum planes (bf16)
    unsigned short* G2B  = (unsigned short*)alloc(PLB);
    unsigned short* G3A  = (unsigned short*)alloc(PLB);
    unsigned short* G3B  = (unsigned short*)alloc(PLB);
    unsigned short* G4   = (unsigned short*)alloc(PLB);
    (void)ws_size; (void)in_sizes; (void)n_in; (void)out_size;

    // CSR build (graph static across layers) + initial bf16 convert
    hipMemsetAsync(counts, 0, (size_t)NB * 4, stream);
    k_hist3<<<(NE + 255) / 256, 256, 0, stream>>>(edst, etyp, counts);
    k_cvt<<<(NN * DIM / 4 + 255) / 256, 256, 0, stream>>>(x, xb0);
    k_scanA<<<SCAN_BLK, 1024, 0, stream>>>(counts, rs, bsum);
    k_scanB<<<1, 512, 0, stream>>>(bsum, bexcl, rs);
    k_scanC<<<SCAN_BLK, 1024, 0, stream>>>(rs, cursor, bexcl);
    k_scatter3<<<(NE + 255) / 256, 256, 0, stream>>>(esrc, edst, etyp, ehop, cursor, src_s);

    const int ga = (NN * DIM + 255) / 256;   // one wave per node
    const int gm = NN_PAD / 64;              // 782 blocks, 64-node tile, 256 thr

    // t = 0: write G2[0],G3[0],G4[0]; no hop row
    k_agg<0><<<ga, 256, 0, stream>>>(rs, src_s, xb0, nu_edge, nu_kt,
                                     G4, G4, G4, aAll, G2A, G3A, G4);
    k_mm<0><<<gm, 256, 0, stream>>>(aAll, W_edge, b_edge, nu_edge, W_t, b_t, nu_kt,
                                    x, hA, hAb);
    // t = 1: write G2[1],G3[1]; hop row = nk2*G2[0]
    k_agg<1><<<ga, 256, 0, stream>>>(rs, src_s, hAb, nu_edge, nu_kt,
                                     G2A, G4, G4, aAll, G2B, G3B, G4);
    k_mm<1><<<gm, 256, 0, stream>>>(aAll, W_edge, b_edge, nu_edge, W_t, b_t, nu_kt,
                                    hA, hB, hBb);
    // t = 2: write G2[2] (->G2A, layer-0 content consumed at t=1);
    //        hop row = nk2*G2[1] + nk3*G3[0]
    k_agg<2><<<ga, 256, 0, stream>>>(rs, src_s, hBb, nu_edge, nu_kt,
                                     G2B, G3A, G4, aAll, G2A, G3A, G4);
    k_mm<2><<<gm, 256, 0, stream>>>(aAll, W_edge, b_edge, nu_edge, W_t, b_t, nu_kt,
                                    hB, hA, hAb);
    // t = 3: no G writes; hop row = nk2*G2[2] + nk3*G3[1] + nk4*G4[0]
    k_agg<3><<<ga, 256, 0, stream>>>(rs, src_s, hAb, nu_edge, nu_kt,
                                     G2A, G3B, G4, aAll, G2B, G3B, G4);
    k_mm<3><<<gm, 256, 0, stream>>>(aAll, W_edge, b_edge, nu_edge, W_t, b_t, nu_kt,
                                    hA, out, (unsigned short*)nullptr);
}

// Round 13
// 374.768 us; speedup vs baseline: 1.6868x; 1.1696x over previous
//
#include <hip/hip_runtime.h>

#define NN 50000
#define NN_PAD 50048                    // 64-aligned, covers last k_mm tile
#define NE 800000
#define DIM 64
#define TL 4
#define ET 3
#define MH 6
#define NBKT 3
#define NB (NN * NBKT)                  // 150000
#define SCAN_BLK ((NB + 1023) / 1024)   // 147

typedef __attribute__((ext_vector_type(8))) short short8;
typedef __attribute__((ext_vector_type(4))) float f32x4;

__device__ __forceinline__ unsigned bf16rne(float f) {
    unsigned b = __float_as_uint(f);
    return (b + 0x7FFFu + ((b >> 16) & 1u)) >> 16;
}
__device__ __forceinline__ float bf2f(unsigned short u) {
    return __uint_as_float((unsigned)u << 16);
}

// ---------------- CSR build: 3 type buckets per node, hop packed in entry ----------------

static __global__ void k_hist3(const int* __restrict__ dst, const int* __restrict__ typ,
                               int* __restrict__ counts) {
    int e = blockIdx.x * blockDim.x + threadIdx.x;
    if (e >= NE) return;
    atomicAdd(&counts[dst[e] * NBKT + typ[e]], 1);
}

static __global__ void k_scanA(const int* __restrict__ counts, int* __restrict__ rs,
                               int* __restrict__ bsum) {
    __shared__ int sm[1024];
    int idx = blockIdx.x * 1024 + threadIdx.x;
    int v = (idx < NB) ? counts[idx] : 0;
    sm[threadIdx.x] = v;
    __syncthreads();
    for (int off = 1; off < 1024; off <<= 1) {
        int t = (threadIdx.x >= off) ? sm[threadIdx.x - off] : 0;
        __syncthreads();
        sm[threadIdx.x] += t;
        __syncthreads();
    }
    if (idx < NB) rs[idx] = sm[threadIdx.x] - v;   // exclusive within block
    if (threadIdx.x == 1023) bsum[blockIdx.x] = sm[1023];
}

static __global__ void k_scanB(const int* __restrict__ bsum, int* __restrict__ bexcl,
                               int* __restrict__ rs) {
    __shared__ int sm[512];
    int tid = threadIdx.x;
    int v = (tid < SCAN_BLK) ? bsum[tid] : 0;
    sm[tid] = v;
    __syncthreads();
    for (int off = 1; off < 512; off <<= 1) {
        int t = (tid >= off) ? sm[tid - off] : 0;
        __syncthreads();
        sm[tid] += t;
        __syncthreads();
    }
    if (tid < SCAN_BLK) bexcl[tid] = sm[tid] - v;
    if (tid == 511) rs[NB] = sm[511];              // grand total
}

static __global__ void k_scanC(int* __restrict__ rs, int* __restrict__ cursor,
                               const int* __restrict__ bexcl) {
    int idx = blockIdx.x * 1024 + threadIdx.x;
    if (idx >= NB) return;
    int r = rs[idx] + bexcl[blockIdx.x];
    rs[idx] = r;
    cursor[idx] = r;
}

static __global__ void k_scatter3(const int* __restrict__ src, const int* __restrict__ dst,
                                  const int* __restrict__ typ, const int* __restrict__ hop,
                                  int* __restrict__ cursor, unsigned int* __restrict__ src_s) {
    int e = blockIdx.x * blockDim.x + threadIdx.x;
    if (e >= NE) return;
    int slot = atomicAdd(&cursor[dst[e] * NBKT + typ[e]], 1);
    src_s[slot] = (unsigned int)src[e] | ((unsigned int)hop[e] << 16);
}

// ---------------- f32 -> bf16 plane convert (initial x only) ----------------

static __global__ void k_cvt(const float* __restrict__ in, unsigned short* __restrict__ out) {
    int i = blockIdx.x * blockDim.x + threadIdx.x;   // one float4 per thread
    if (i >= NN * DIM / 4) return;
    float4 v = ((const float4*)in)[i];
    uint2 p;
    p.x = bf16rne(v.x) | (bf16rne(v.y) << 16);
    p.y = bf16rne(v.z) | (bf16rne(v.w) << 16);
    ((uint2*)out)[i] = p;
}

// ---------------- W pre-pack to bf16 in MFMA B-fragment order --------------------------
// Bpack[((T*4+nt)*8+ks)*512 + lane*8 + j] = Wcat_T[ks*32 + 8*(lane>>4) + j][nt*16 + lane&15]
// Same (group,reg)->k labeling as the A-side loads, so any internal MFMA k-map works.

static __global__ void k_pack(const float* __restrict__ W_edge, const float* __restrict__ W_t,
                              unsigned short* __restrict__ Bpack) {
    int idx = blockIdx.x * 256 + threadIdx.x;   // 65536 total
    if (idx >= 4 * 4 * 8 * 512) return;
    int j = idx & 7;
    int lane = (idx >> 3) & 63;
    int ks = (idx >> 9) & 7;
    int nt = (idx >> 12) & 3;
    int T = idx >> 14;
    int d = ks * 32 + 8 * (lane >> 4) + j;     // k within [0,256)
    int n = nt * 16 + (lane & 15);
    int m = d >> 6, dd = d & 63;
    float v;
    if (m < 3) v = W_edge[(((size_t)m * TL + T) * DIM + dd) * DIM + n];
    else if (T >= 1) v = W_t[((size_t)T * DIM + dd) * DIM + n];
    else v = 0.f;                               // T=0 never reads ks>=6
    Bpack[idx] = (unsigned short)bf16rne(v);
}

// ---------------- Aggregation: one wave per node; bf16 gathers; node-major A rows --------

template <int T>
static __global__ __launch_bounds__(256) void k_agg(
        const int* __restrict__ rs, const unsigned int* __restrict__ src_s,
        const unsigned short* __restrict__ xb,
        const float* __restrict__ nu_edge, const float* __restrict__ nu_kt,
        const unsigned short* __restrict__ gp2, const unsigned short* __restrict__ gp3,
        const unsigned short* __restrict__ gp4,
        unsigned short* __restrict__ aAll, unsigned short* __restrict__ g2,
        unsigned short* __restrict__ g3, unsigned short* __restrict__ g4) {
    int g = blockIdx.x * blockDim.x + threadIdx.x;
    int node = g >> 6;
    if (node >= NN) return;
    int lane = g & 63;
    const size_t po = (size_t)node * DIM + lane;

    // hop A-row for this layer's matmul: coalesced bf16 loads, independent of gather loop
    float hp = 0.f;
    if (T >= 1) {
        hp = nu_kt[T * MH + 2] * bf2f(gp2[po]);
        if (T >= 2) hp = fmaf(nu_kt[T * MH + 3], bf2f(gp3[po]), hp);
        if (T >= 3) hp = fmaf(nu_kt[T * MH + 4], bf2f(gp4[po]), hp);
    }

    int ro = 0;
    if (lane < 4) ro = rs[node * NBKT + lane];
    const int b0 = __builtin_amdgcn_readlane(ro, 0);
    const int b1 = __builtin_amdgcn_readlane(ro, 1);
    const int b2 = __builtin_amdgcn_readlane(ro, 2);
    const int b3 = __builtin_amdgcn_readlane(ro, 3);
    const int nt = b3 - b0, t1 = b1 - b0, t2 = b2 - b0;

    float s0 = 0.f, s1 = 0.f, s2 = 0.f;
    float h2 = 0.f, h3 = 0.f, h4 = 0.f;

    if (nt <= 64) {
        int sv = (lane < nt) ? (int)src_s[b0 + lane] : 0;
#pragma unroll 16
        for (int i = 0; i < nt; ++i) {
            unsigned int sp = (unsigned int)__builtin_amdgcn_readlane(sv, i);  // SGPR
            int srcn = (int)(sp & 0xFFFFu);
            int hop = (int)(sp >> 16);
            float v = bf2f(xb[(size_t)srcn * DIM + lane]);
            s0 = fmaf((i < t1) ? 1.f : 0.f, v, s0);
            s1 = fmaf((i >= t1 && i < t2) ? 1.f : 0.f, v, s1);
            s2 = fmaf((i >= t2) ? 1.f : 0.f, v, s2);
            if (T <= 2) h2 = fmaf((hop == 2) ? 1.f : 0.f, v, h2);
            if (T <= 1) h3 = fmaf((hop == 3) ? 1.f : 0.f, v, h3);
            if (T == 0) h4 = fmaf((hop == 4) ? 1.f : 0.f, v, h4);
        }
    } else {
#pragma unroll 4
        for (int i = 0; i < nt; ++i) {
            unsigned int sp = src_s[b0 + i];           // uniform address, broadcast
            int srcn = (int)(sp & 0xFFFFu);
            int hop = (int)(sp >> 16);
            float v = bf2f(xb[(size_t)srcn * DIM + lane]);
            s0 = fmaf((i < t1) ? 1.f : 0.f, v, s0);
            s1 = fmaf((i >= t1 && i < t2) ? 1.f : 0.f, v, s1);
            s2 = fmaf((i >= t2) ? 1.f : 0.f, v, s2);
            if (T <= 2) h2 = fmaf((hop == 2) ? 1.f : 0.f, v, h2);
            if (T <= 1) h3 = fmaf((hop == 3) ? 1.f : 0.f, v, h3);
            if (T == 0) h4 = fmaf((hop == 4) ? 1.f : 0.f, v, h4);
        }
    }

    float nu0 = nu_edge[0 * TL + T], nu1 = nu_edge[1 * TL + T], nu2 = nu_edge[2 * TL + T];
    unsigned short* __restrict__ Ar = aAll + (size_t)node * 256;   // [node][m*64+lane]
    Ar[0 * DIM + lane] = (unsigned short)bf16rne(nu0 * s0);
    Ar[1 * DIM + lane] = (unsigned short)bf16rne(nu1 * s1);
    Ar[2 * DIM + lane] = (unsigned short)bf16rne(nu2 * s2);
    if (T >= 1) Ar[3 * DIM + lane] = (unsigned short)bf16rne(hp);
    if (T <= 2) g2[po] = (unsigned short)bf16rne(h2);
    if (T <= 1) g3[po] = (unsigned short)bf16rne(h3);
    if (T == 0) g4[po] = (unsigned short)bf16rne(h4);
}

// ---------------- Matmul via MFMA: A[50048x256]bf16 @ B[256x64]bf16, fused epilogue ------
// Block = 256 thr / 64 nodes; wave w -> 16-row strip m0 = blk*64 + w*16.
// Per wave: KST k-steps x 4 n-tiles of mfma_f32_16x16x32_bf16.

template <int T>
static __global__ __launch_bounds__(256) void k_mm(
        const unsigned short* __restrict__ aAll,
        const unsigned short* __restrict__ Bpack,
        const float* __restrict__ b_edge, const float* __restrict__ nu_edge,
        const float* __restrict__ b_t, const float* __restrict__ nu_kt,
        const float* __restrict__ xin, float* __restrict__ xout,
        unsigned short* __restrict__ xbo) {
    constexpr int KST = (T >= 1) ? 8 : 6;
    const int w = __builtin_amdgcn_readfirstlane(threadIdx.x >> 6);
    const int l = threadIdx.x & 63;
    const int g = l >> 4, i = l & 15;
    const int m0 = blockIdx.x * 64 + w * 16;

    const float nu0 = nu_edge[0 * TL + T], nu1 = nu_edge[1 * TL + T],
                nu2 = nu_edge[2 * TL + T];
    float nsum = 0.f;
    if (T >= 1) {
        nsum = nu_kt[T * MH + 2];
        if (T >= 2) nsum += nu_kt[T * MH + 3];
        if (T >= 3) nsum += nu_kt[T * MH + 4];
    }

    f32x4 acc[4];
#pragma unroll
    for (int nt = 0; nt < 4; ++nt) {
        int col = nt * 16 + i;
        float b = nu0 * b_edge[(0 * TL + T) * DIM + col]
                + nu1 * b_edge[(1 * TL + T) * DIM + col]
                + nu2 * b_edge[(2 * TL + T) * DIM + col];
        if (T >= 1) b = fmaf(nsum, b_t[T * DIM + col], b);
        acc[nt] = (f32x4){b, b, b, b};
    }

    // A: row = m0+i, k = ks*32 + 8g + [0..8)  -> one uint4 per k-step
    const uint4* __restrict__ Abase = (const uint4*)(aAll + (size_t)(m0 + i) * 256 + g * 8);
    const uint4* __restrict__ Bu = (const uint4*)Bpack;

#pragma unroll
    for (int ks = 0; ks < KST; ++ks) {
        short8 a = __builtin_bit_cast(short8, Abase[ks * 4]);
#pragma unroll
        for (int nt = 0; nt < 4; ++nt) {
            short8 b = __builtin_bit_cast(short8, Bu[(((size_t)T * 4 + nt) * 8 + ks) * 64 + l]);
            acc[nt] = __builtin_amdgcn_mfma_f32_16x16x32_bf16(a, b, acc[nt], 0, 0, 0);
        }
    }

    // D: row = m0 + 4g + r, col = nt*16 + i  (m89-verified mapping)
#pragma unroll
    for (int nt = 0; nt < 4; ++nt) {
        int col = nt * 16 + i;
#pragma unroll
        for (int r = 0; r < 4; ++r) {
            int node = m0 + 4 * g + r;
            if (node < NN) {
                size_t idx = (size_t)node * DIM + col;
                float v = acc[nt][r];
                v = v > 0.f ? v : 0.f;
                float o = xin[idx] + v;
                xout[idx] = o;
                if (xbo) xbo[idx] = (unsigned short)bf16rne(o);
            }
        }
    }
}

// ---------------- Host ----------------

extern "C" void kernel_launch(void* const* d_in, const int* in_sizes, int n_in,
                              void* d_out, int out_size, void* d_ws, size_t ws_size,
                              hipStream_t stream) {
    const float* x       = (const float*)d_in[0];
    const float* W_edge  = (const float*)d_in[1];
    const float* b_edge  = (const float*)d_in[2];
    const float* nu_edge = (const float*)d_in[3];
    const float* W_t     = (const float*)d_in[4];
    const float* b_t     = (const float*)d_in[5];
    const float* nu_kt   = (const float*)d_in[6];
    const int* esrc = (const int*)d_in[7];
    const int* edst = (const int*)d_in[8];
    const int* ehop = (const int*)d_in[9];
    const int* etyp = (const int*)d_in[10];
    float* out = (float*)d_out;

    char* ws = (char*)d_ws;
    size_t off = 0;
    auto alloc = [&](size_t bytes) {
        void* p = ws + off;
        off = (off + bytes + 255) & ~(size_t)255;
        return p;
    };
    const size_t PL  = (size_t)NN * DIM * 4;         // f32 feature plane
    const size_t PLB = (size_t)NN * DIM * 2;         // bf16 feature plane
    int* counts = (int*)alloc((size_t)NB * 4);
    int* rs     = (int*)alloc(((size_t)NB + 1) * 4);
    int* cursor = (int*)alloc((size_t)NB * 4);
    int* bsum   = (int*)alloc(1024 * 4);
    int* bexcl  = (int*)alloc(1024 * 4);
    unsigned int* src_s = (unsigned int*)alloc((size_t)NE * 4);
    float* hA   = (float*)alloc(PL);                 // ping-pong layer outputs (f32)
    float* hB   = (float*)alloc(PL);
    unsigned short* xb0 = (unsigned short*)alloc(PLB);   // bf16 shadows
    unsigned short* hAb = (unsigned short*)alloc(PLB);
    unsigned short* hBb = (unsigned short*)alloc(PLB);
    unsigned short* aAll  = (unsigned short*)alloc((size_t)NN_PAD * 256 * 2);  // [node][256] bf16
    unsigned short* Bpack = (unsigned short*)alloc((size_t)4 * 4 * 8 * 512 * 2);
    unsigned short* G2A  = (unsigned short*)alloc(PLB);  // rolling hop-sum planes (bf16)
    unsigned short* G2B  = (unsigned short*)alloc(PLB);
    unsigned short* G3A  = (unsigned short*)alloc(PLB);
    unsigned short* G3B  = (unsigned short*)alloc(PLB);
    unsigned short* G4   = (unsigned short*)alloc(PLB);
    (void)ws_size; (void)in_sizes; (void)n_in; (void)out_size;

    // CSR build (graph static across layers) + bf16 converts + W pre-pack
    hipMemsetAsync(counts, 0, (size_t)NB * 4, stream);
    k_hist3<<<(NE + 255) / 256, 256, 0, stream>>>(edst, etyp, counts);
    k_cvt<<<(NN * DIM / 4 + 255) / 256, 256, 0, stream>>>(x, xb0);
    k_pack<<<256, 256, 0, stream>>>(W_edge, W_t, Bpack);
    k_scanA<<<SCAN_BLK, 1024, 0, stream>>>(counts, rs, bsum);
    k_scanB<<<1, 512, 0, stream>>>(bsum, bexcl, rs);
    k_scanC<<<SCAN_BLK, 1024, 0, stream>>>(rs, cursor, bexcl);
    k_scatter3<<<(NE + 255) / 256, 256, 0, stream>>>(esrc, edst, etyp, ehop, cursor, src_s);

    const int ga = (NN * DIM + 255) / 256;   // one wave per node
    const int gm = NN_PAD / 64;              // 782 blocks, 64-node tile, 256 thr

    // t = 0: write G2[0],G3[0],G4[0]; no hop row (KST=6 skips hop segment)
    k_agg<0><<<ga, 256, 0, stream>>>(rs, src_s, xb0, nu_edge, nu_kt,
                                     G4, G4, G4, aAll, G2A, G3A, G4);
    k_mm<0><<<gm, 256, 0, stream>>>(aAll, Bpack, b_edge, nu_edge, b_t, nu_kt,
                                    x, hA, hAb);
    // t = 1: write G2[1],G3[1]; hop row = nk2*G2[0]
    k_agg<1><<<ga, 256, 0, stream>>>(rs, src_s, hAb, nu_edge, nu_kt,
                                     G2A, G4, G4, aAll, G2B, G3B, G4);
    k_mm<1><<<gm, 256, 0, stream>>>(aAll, Bpack, b_edge, nu_edge, b_t, nu_kt,
                                    hA, hB, hBb);
    // t = 2: write G2[2] (->G2A, layer-0 content consumed at t=1);
    //        hop row = nk2*G2[1] + nk3*G3[0]
    k_agg<2><<<ga, 256, 0, stream>>>(rs, src_s, hBb, nu_edge, nu_kt,
                                     G2B, G3A, G4, aAll, G2A, G3A, G4);
    k_mm<2><<<gm, 256, 0, stream>>>(aAll, Bpack, b_edge, nu_edge, b_t, nu_kt,
                                    hB, hA, hAb);
    // t = 3: no G writes; hop row = nk2*G2[2] + nk3*G3[1] + nk4*G4[0]
    k_agg<3><<<ga, 256, 0, stream>>>(rs, src_s, hAb, nu_edge, nu_kt,
                                     G2A, G3B, G4, aAll, G2B, G3B, G4);
    k_mm<3><<<gm, 256, 0, stream>>>(aAll, Bpack, b_edge, nu_edge, b_t, nu_kt,
                                    hA, out, (unsigned short*)nullptr);
}

// Round 14
// 369.982 us; speedup vs baseline: 1.7087x; 1.0129x over previous
//
#include <hip/hip_runtime.h>

#define NN 50000
#define NN_PAD 50048                    // 64-aligned, covers last k_mm tile
#define NE 800000
#define DIM 64
#define TL 4
#define ET 3
#define MH 6
#define NBKT 3
#define NB (NN * NBKT)                  // 150000
#define SCAN_BLK ((NB + 1023) / 1024)   // 147

typedef __attribute__((ext_vector_type(8))) short short8;
typedef __attribute__((ext_vector_type(4))) float f32x4;

__device__ __forceinline__ unsigned bf16rne(float f) {
    unsigned b = __float_as_uint(f);
    return (b + 0x7FFFu + ((b >> 16) & 1u)) >> 16;
}
__device__ __forceinline__ float bf2f(unsigned short u) {
    return __uint_as_float((unsigned)u << 16);
}

// ---------------- CSR build: 3 type buckets per node, hop packed in entry ----------------
// Streaming reads are non-temporal so they don't evict the scatter target lines from L2.

static __global__ void k_hist3(const int* __restrict__ dst, const int* __restrict__ typ,
                               int* __restrict__ counts) {
    int e0 = (blockIdx.x * blockDim.x + threadIdx.x) * 2;
    if (e0 >= NE) return;
    int d0 = __builtin_nontemporal_load(dst + e0);
    int d1 = __builtin_nontemporal_load(dst + e0 + 1);
    int t0 = __builtin_nontemporal_load(typ + e0);
    int t1 = __builtin_nontemporal_load(typ + e0 + 1);
    atomicAdd(&counts[d0 * NBKT + t0], 1);
    atomicAdd(&counts[d1 * NBKT + t1], 1);
}

static __global__ void k_scanA(const int* __restrict__ counts, int* __restrict__ rs,
                               int* __restrict__ bsum) {
    __shared__ int sm[1024];
    int idx = blockIdx.x * 1024 + threadIdx.x;
    int v = (idx < NB) ? counts[idx] : 0;
    sm[threadIdx.x] = v;
    __syncthreads();
    for (int off = 1; off < 1024; off <<= 1) {
        int t = (threadIdx.x >= off) ? sm[threadIdx.x - off] : 0;
        __syncthreads();
        sm[threadIdx.x] += t;
        __syncthreads();
    }
    if (idx < NB) rs[idx] = sm[threadIdx.x] - v;   // exclusive within block
    if (threadIdx.x == 1023) bsum[blockIdx.x] = sm[1023];
}

static __global__ void k_scanB(const int* __restrict__ bsum, int* __restrict__ bexcl,
                               int* __restrict__ rs) {
    __shared__ int sm[512];
    int tid = threadIdx.x;
    int v = (tid < SCAN_BLK) ? bsum[tid] : 0;
    sm[tid] = v;
    __syncthreads();
    for (int off = 1; off < 512; off <<= 1) {
        int t = (tid >= off) ? sm[tid - off] : 0;
        __syncthreads();
        sm[tid] += t;
        __syncthreads();
    }
    if (tid < SCAN_BLK) bexcl[tid] = sm[tid] - v;
    if (tid == 511) rs[NB] = sm[511];              // grand total
}

static __global__ void k_scanC(int* __restrict__ rs, int* __restrict__ cursor,
                               const int* __restrict__ bexcl) {
    int idx = blockIdx.x * 1024 + threadIdx.x;
    if (idx >= NB) return;
    int r = rs[idx] + bexcl[blockIdx.x];
    rs[idx] = r;
    cursor[idx] = r;
}

static __global__ void k_scatter3(const int* __restrict__ src, const int* __restrict__ dst,
                                  const int* __restrict__ typ, const int* __restrict__ hop,
                                  int* __restrict__ cursor, unsigned int* __restrict__ src_s) {
    int e0 = (blockIdx.x * blockDim.x + threadIdx.x) * 2;
    if (e0 >= NE) return;
    int d0 = __builtin_nontemporal_load(dst + e0);
    int d1 = __builtin_nontemporal_load(dst + e0 + 1);
    int t0 = __builtin_nontemporal_load(typ + e0);
    int t1 = __builtin_nontemporal_load(typ + e0 + 1);
    int s0 = __builtin_nontemporal_load(src + e0);
    int s1 = __builtin_nontemporal_load(src + e0 + 1);
    int h0 = __builtin_nontemporal_load(hop + e0);
    int h1 = __builtin_nontemporal_load(hop + e0 + 1);
    int slot0 = atomicAdd(&cursor[d0 * NBKT + t0], 1);
    src_s[slot0] = (unsigned int)s0 | ((unsigned int)h0 << 16);
    int slot1 = atomicAdd(&cursor[d1 * NBKT + t1], 1);
    src_s[slot1] = (unsigned int)s1 | ((unsigned int)h1 << 16);
}

// ---------------- f32 -> bf16 plane convert (initial x only) ----------------

static __global__ void k_cvt(const float* __restrict__ in, unsigned short* __restrict__ out) {
    int i = blockIdx.x * blockDim.x + threadIdx.x;   // one float4 per thread
    if (i >= NN * DIM / 4) return;
    float4 v = ((const float4*)in)[i];
    uint2 p;
    p.x = bf16rne(v.x) | (bf16rne(v.y) << 16);
    p.y = bf16rne(v.z) | (bf16rne(v.w) << 16);
    ((uint2*)out)[i] = p;
}

// ---------------- W pre-pack, interleaved k-map: k = 4*dd + m --------------------------
// Bpack[((T*4+nt)*8+ks)*512 + lane*8 + j] = Wcat_T[k = ks*32+8*(lane>>4)+j][nt*16+lane&15]
// with Wcat row k -> matrix m = k&3, row dd = k>>2. A-side uses the same labeling.

static __global__ void k_pack(const float* __restrict__ W_edge, const float* __restrict__ W_t,
                              unsigned short* __restrict__ Bpack) {
    int idx = blockIdx.x * 256 + threadIdx.x;   // 65536 total
    if (idx >= 4 * 4 * 8 * 512) return;
    int j = idx & 7;
    int lane = (idx >> 3) & 63;
    int ks = (idx >> 9) & 7;
    int nt = (idx >> 12) & 3;
    int T = idx >> 14;
    int k = ks * 32 + 8 * (lane >> 4) + j;     // k within [0,256)
    int n = nt * 16 + (lane & 15);
    int m = k & 3, dd = k >> 2;
    float v;
    if (m < 3) v = W_edge[(((size_t)m * TL + T) * DIM + dd) * DIM + n];
    else if (T >= 1) v = W_t[((size_t)T * DIM + dd) * DIM + n];
    else v = 0.f;                               // T=0: hop slice contributes zero
    Bpack[idx] = (unsigned short)bf16rne(v);
}

// ---------------- Aggregation: one wave per node; per-bucket sub-loops; packed A store ---

template <int T>
static __global__ __launch_bounds__(256) void k_agg(
        const int* __restrict__ rs, const unsigned int* __restrict__ src_s,
        const unsigned short* __restrict__ xb,
        const float* __restrict__ nu_edge, const float* __restrict__ nu_kt,
        const unsigned short* __restrict__ gp2, const unsigned short* __restrict__ gp3,
        const unsigned short* __restrict__ gp4,
        unsigned short* __restrict__ aAll, unsigned short* __restrict__ g2,
        unsigned short* __restrict__ g3, unsigned short* __restrict__ g4) {
    int g = blockIdx.x * blockDim.x + threadIdx.x;
    int node = g >> 6;
    if (node >= NN) return;
    int lane = g & 63;
    const size_t po = (size_t)node * DIM + lane;

    // hop A-row for this layer's matmul: coalesced bf16 loads, independent of gather loop
    float hp = 0.f;
    if (T >= 1) {
        hp = nu_kt[T * MH + 2] * bf2f(gp2[po]);
        if (T >= 2) hp = fmaf(nu_kt[T * MH + 3], bf2f(gp3[po]), hp);
        if (T >= 3) hp = fmaf(nu_kt[T * MH + 4], bf2f(gp4[po]), hp);
    }

    int ro = 0;
    if (lane < 4) ro = rs[node * NBKT + lane];
    const int b0 = __builtin_amdgcn_readlane(ro, 0);
    const int b1 = __builtin_amdgcn_readlane(ro, 1);
    const int b2 = __builtin_amdgcn_readlane(ro, 2);
    const int b3 = __builtin_amdgcn_readlane(ro, 3);
    const int nt = b3 - b0, t1 = b1 - b0, t2 = b2 - b0;

    float s0 = 0.f, s1 = 0.f, s2 = 0.f;
    float h2 = 0.f, h3 = 0.f, h4 = 0.f;

#define EDGE_BODY(SPEXPR, ACC)                                                   \
    {                                                                            \
        unsigned int sp = (SPEXPR);                                              \
        int srcn = (int)(sp & 0xFFFFu);                                          \
        float v = bf2f(xb[(size_t)srcn * DIM + lane]);                           \
        ACC += v;                                                                \
        if (T <= 2) {                                                            \
            int hop = (int)(sp >> 16);                                           \
            h2 = fmaf((hop == 2) ? 1.f : 0.f, v, h2);                            \
            if (T <= 1) h3 = fmaf((hop == 3) ? 1.f : 0.f, v, h3);                \
            if (T == 0) h4 = fmaf((hop == 4) ? 1.f : 0.f, v, h4);                \
        }                                                                        \
    }

    if (nt <= 64) {
        int sv = (lane < nt) ? (int)src_s[b0 + lane] : 0;
#pragma unroll 8
        for (int i = 0; i < t1; ++i)
            EDGE_BODY((unsigned int)__builtin_amdgcn_readlane(sv, i), s0)
#pragma unroll 8
        for (int i = t1; i < t2; ++i)
            EDGE_BODY((unsigned int)__builtin_amdgcn_readlane(sv, i), s1)
#pragma unroll 8
        for (int i = t2; i < nt; ++i)
            EDGE_BODY((unsigned int)__builtin_amdgcn_readlane(sv, i), s2)
    } else {
#pragma unroll 4
        for (int i = 0; i < t1; ++i) EDGE_BODY(src_s[b0 + i], s0)
#pragma unroll 4
        for (int i = t1; i < t2; ++i) EDGE_BODY(src_s[b0 + i], s1)
#pragma unroll 4
        for (int i = t2; i < nt; ++i) EDGE_BODY(src_s[b0 + i], s2)
    }
#undef EDGE_BODY

    float nu0 = nu_edge[0 * TL + T], nu1 = nu_edge[1 * TL + T], nu2 = nu_edge[2 * TL + T];
    // packed A row: [node][d*4 + m], lane=d -> one uint2 store
    uint2 pk;
    pk.x = bf16rne(nu0 * s0) | (bf16rne(nu1 * s1) << 16);
    pk.y = bf16rne(nu2 * s2) | (bf16rne(hp) << 16);
    *(uint2*)(aAll + (size_t)node * 256 + lane * 4) = pk;
    if (T <= 2) g2[po] = (unsigned short)bf16rne(h2);
    if (T <= 1) g3[po] = (unsigned short)bf16rne(h3);
    if (T == 0) g4[po] = (unsigned short)bf16rne(h4);
}

// ---------------- Matmul via MFMA: A[50048x256]bf16 @ B[256x64]bf16, fused epilogue ------

template <int T>
static __global__ __launch_bounds__(256) void k_mm(
        const unsigned short* __restrict__ aAll,
        const unsigned short* __restrict__ Bpack,
        const float* __restrict__ b_edge, const float* __restrict__ nu_edge,
        const float* __restrict__ b_t, const float* __restrict__ nu_kt,
        const float* __restrict__ xin, float* __restrict__ xout,
        unsigned short* __restrict__ xbo) {
    const int w = __builtin_amdgcn_readfirstlane(threadIdx.x >> 6);
    const int l = threadIdx.x & 63;
    const int g = l >> 4, i = l & 15;
    const int m0 = blockIdx.x * 64 + w * 16;

    const float nu0 = nu_edge[0 * TL + T], nu1 = nu_edge[1 * TL + T],
                nu2 = nu_edge[2 * TL + T];
    float nsum = 0.f;
    if (T >= 1) {
        nsum = nu_kt[T * MH + 2];
        if (T >= 2) nsum += nu_kt[T * MH + 3];
        if (T >= 3) nsum += nu_kt[T * MH + 4];
    }

    f32x4 acc[4];
#pragma unroll
    for (int nt = 0; nt < 4; ++nt) {
        int col = nt * 16 + i;
        float b = nu0 * b_edge[(0 * TL + T) * DIM + col]
                + nu1 * b_edge[(1 * TL + T) * DIM + col]
                + nu2 * b_edge[(2 * TL + T) * DIM + col];
        if (T >= 1) b = fmaf(nsum, b_t[T * DIM + col], b);
        acc[nt] = (f32x4){b, b, b, b};
    }

    // A: row = m0+i, k = ks*32 + 8g + [0..8)  -> one uint4 per k-step
    const uint4* __restrict__ Abase = (const uint4*)(aAll + (size_t)(m0 + i) * 256 + g * 8);
    const uint4* __restrict__ Bu = (const uint4*)Bpack;

#pragma unroll
    for (int ks = 0; ks < 8; ++ks) {
        short8 a = __builtin_bit_cast(short8, Abase[ks * 4]);
#pragma unroll
        for (int nt = 0; nt < 4; ++nt) {
            short8 b = __builtin_bit_cast(short8, Bu[(((size_t)T * 4 + nt) * 8 + ks) * 64 + l]);
            acc[nt] = __builtin_amdgcn_mfma_f32_16x16x32_bf16(a, b, acc[nt], 0, 0, 0);
        }
    }

    // D: row = m0 + 4g + r, col = nt*16 + i  (m89-verified mapping)
#pragma unroll
    for (int nt = 0; nt < 4; ++nt) {
        int col = nt * 16 + i;
#pragma unroll
        for (int r = 0; r < 4; ++r) {
            int node = m0 + 4 * g + r;
            if (node < NN) {
                size_t idx = (size_t)node * DIM + col;
                float v = acc[nt][r];
                v = v > 0.f ? v : 0.f;
                float o = xin[idx] + v;
                xout[idx] = o;
                if (xbo) xbo[idx] = (unsigned short)bf16rne(o);
            }
        }
    }
}

// ---------------- Host ----------------

extern "C" void kernel_launch(void* const* d_in, const int* in_sizes, int n_in,
                              void* d_out, int out_size, void* d_ws, size_t ws_size,
                              hipStream_t stream) {
    const float* x       = (const float*)d_in[0];
    const float* W_edge  = (const float*)d_in[1];
    const float* b_edge  = (const float*)d_in[2];
    const float* nu_edge = (const float*)d_in[3];
    const float* W_t     = (const float*)d_in[4];
    const float* b_t     = (const float*)d_in[5];
    const float* nu_kt   = (const float*)d_in[6];
    const int* esrc = (const int*)d_in[7];
    const int* edst = (const int*)d_in[8];
    const int* ehop = (const int*)d_in[9];
    const int* etyp = (const int*)d_in[10];
    float* out = (float*)d_out;

    char* ws = (char*)d_ws;
    size_t off = 0;
    auto alloc = [&](size_t bytes) {
        void* p = ws + off;
        off = (off + bytes + 255) & ~(size_t)255;
        return p;
    };
    const size_t PL  = (size_t)NN * DIM * 4;         // f32 feature plane
    const size_t PLB = (size_t)NN * DIM * 2;         // bf16 feature plane
    int* counts = (int*)alloc((size_t)NB * 4);
    int* rs     = (int*)alloc(((size_t)NB + 1) * 4);
    int* cursor = (int*)alloc((size_t)NB * 4);
    int* bsum   = (int*)alloc(1024 * 4);
    int* bexcl  = (int*)alloc(1024 * 4);
    unsigned int* src_s = (unsigned int*)alloc((size_t)NE * 4);
    float* hA   = (float*)alloc(PL);                 // ping-pong layer outputs (f32)
    float* hB   = (float*)alloc(PL);
    unsigned short* xb0 = (unsigned short*)alloc(PLB);   // bf16 shadows
    unsigned short* hAb = (unsigned short*)alloc(PLB);
    unsigned short* hBb = (unsigned short*)alloc(PLB);
    unsigned short* aAll  = (unsigned short*)alloc((size_t)NN_PAD * 256 * 2);  // [node][256] bf16
    unsigned short* Bpack = (unsigned short*)alloc((size_t)4 * 4 * 8 * 512 * 2);
    unsigned short* G2A  = (unsigned short*)alloc(PLB);  // rolling hop-sum planes (bf16)
    unsigned short* G2B  = (unsigned short*)alloc(PLB);
    unsigned short* G3A  = (unsigned short*)alloc(PLB);
    unsigned short* G3B  = (unsigned short*)alloc(PLB);
    unsigned short* G4   = (unsigned short*)alloc(PLB);
    (void)ws_size; (void)in_sizes; (void)n_in; (void)out_size;

    // CSR build (graph static across layers) + bf16 converts + W pre-pack
    hipMemsetAsync(counts, 0, (size_t)NB * 4, stream);
    k_hist3<<<(NE / 2 + 255) / 256, 256, 0, stream>>>(edst, etyp, counts);
    k_cvt<<<(NN * DIM / 4 + 255) / 256, 256, 0, stream>>>(x, xb0);
    k_pack<<<256, 256, 0, stream>>>(W_edge, W_t, Bpack);
    k_scanA<<<SCAN_BLK, 1024, 0, stream>>>(counts, rs, bsum);
    k_scanB<<<1, 512, 0, stream>>>(bsum, bexcl, rs);
    k_scanC<<<SCAN_BLK, 1024, 0, stream>>>(rs, cursor, bexcl);
    k_scatter3<<<(NE / 2 + 255) / 256, 256, 0, stream>>>(esrc, edst, etyp, ehop,
                                                         cursor, src_s);

    const int ga = (NN * DIM + 255) / 256;   // one wave per node
    const int gm = NN_PAD / 64;              // 782 blocks, 64-node tile, 256 thr

    // t = 0: write G2[0],G3[0],G4[0]; no hop row (B hop slice = 0)
    k_agg<0><<<ga, 256, 0, stream>>>(rs, src_s, xb0, nu_edge, nu_kt,
                                     G4, G4, G4, aAll, G2A, G3A, G4);
    k_mm<0><<<gm, 256, 0, stream>>>(aAll, Bpack, b_edge, nu_edge, b_t, nu_kt,
                                    x, hA, hAb);
    // t = 1: write G2[1],G3[1]; hop row = nk2*G2[0]
    k_agg<1><<<ga, 256, 0, stream>>>(rs, src_s, hAb, nu_edge, nu_kt,
                                     G2A, G4, G4, aAll, G2B, G3B, G4);
    k_mm<1><<<gm, 256, 0, stream>>>(aAll, Bpack, b_edge, nu_edge, b_t, nu_kt,
                                    hA, hB, hBb);
    // t = 2: write G2[2] (->G2A, layer-0 content consumed at t=1);
    //        hop row = nk2*G2[1] + nk3*G3[0]
    k_agg<2><<<ga, 256, 0, stream>>>(rs, src_s, hBb, nu_edge, nu_kt,
                                     G2B, G3A, G4, aAll, G2A, G3A, G4);
    k_mm<2><<<gm, 256, 0, stream>>>(aAll, Bpack, b_edge, nu_edge, b_t, nu_kt,
                                    hB, hA, hAb);
    // t = 3: no G writes; hop row = nk2*G2[2] + nk3*G3[1] + nk4*G4[0]
    k_agg<3><<<ga, 256, 0, stream>>>(rs, src_s, hAb, nu_edge, nu_kt,
                                     G2A, G3B, G4, aAll, G2B, G3B, G4);
    k_mm<3><<<gm, 256, 0, stream>>>(aAll, Bpack, b_edge, nu_edge, b_t, nu_kt,
                                    hA, out, (unsigned short*)nullptr);
}

// Round 15
// 365.685 us; speedup vs baseline: 1.7287x; 1.0118x over previous
//
#include <hip/hip_runtime.h>

#define NN 50000
#define NN_PAD 50048                    // 64-aligned, covers last k_mm tile
#define NE 800000
#define DIM 64
#define TL 4
#define ET 3
#define MH 6
#define NBKT 3
#define NB (NN * NBKT)                  // 150000
#define SCAN_BLK ((NB + 1023) / 1024)   // 147
#define SC_CHUNK 2048                   // edges per scatter slice
#define SC_SLICES ((NE + SC_CHUNK - 1) / SC_CHUNK)   // 391

typedef __attribute__((ext_vector_type(8))) short short8;
typedef __attribute__((ext_vector_type(4))) float f32x4;

__device__ __forceinline__ unsigned bf16rne(float f) {
    unsigned b = __float_as_uint(f);
    return (b + 0x7FFFu + ((b >> 16) & 1u)) >> 16;
}
__device__ __forceinline__ float bf2f(unsigned short u) {
    return __uint_as_float((unsigned)u << 16);
}

// ---------------- CSR build: 3 type buckets per node, hop packed in entry ----------------

static __global__ void k_hist3(const int* __restrict__ dst, const int* __restrict__ typ,
                               int* __restrict__ counts) {
    int e = blockIdx.x * blockDim.x + threadIdx.x;
    if (e >= NE) return;
    atomicAdd(&counts[dst[e] * NBKT + typ[e]], 1);
}

static __global__ void k_scanA(const int* __restrict__ counts, int* __restrict__ rs,
                               int* __restrict__ bsum) {
    __shared__ int sm[1024];
    int idx = blockIdx.x * 1024 + threadIdx.x;
    int v = (idx < NB) ? counts[idx] : 0;
    sm[threadIdx.x] = v;
    __syncthreads();
    for (int off = 1; off < 1024; off <<= 1) {
        int t = (threadIdx.x >= off) ? sm[threadIdx.x - off] : 0;
        __syncthreads();
        sm[threadIdx.x] += t;
        __syncthreads();
    }
    if (idx < NB) rs[idx] = sm[threadIdx.x] - v;   // exclusive within block
    if (threadIdx.x == 1023) bsum[blockIdx.x] = sm[1023];
}

static __global__ void k_scanB(const int* __restrict__ bsum, int* __restrict__ bexcl,
                               int* __restrict__ rs) {
    __shared__ int sm[512];
    int tid = threadIdx.x;
    int v = (tid < SCAN_BLK) ? bsum[tid] : 0;
    sm[tid] = v;
    __syncthreads();
    for (int off = 1; off < 512; off <<= 1) {
        int t = (tid >= off) ? sm[tid - off] : 0;
        __syncthreads();
        sm[tid] += t;
        __syncthreads();
    }
    if (tid < SCAN_BLK) bexcl[tid] = sm[tid] - v;
    if (tid == 511) rs[NB] = sm[511];              // grand total
}

static __global__ void k_scanC(int* __restrict__ rs, int* __restrict__ cursor,
                               const int* __restrict__ bexcl) {
    int idx = blockIdx.x * 1024 + threadIdx.x;
    if (idx >= NB) return;
    int r = rs[idx] + bexcl[blockIdx.x];
    rs[idx] = r;
    cursor[idx] = r;
}

// XCD-affine scatter: range = blockIdx & 7 == XCD id (round-robin dispatch), so each
// src_s / cursor cache line is written by ONE XCD only -> no cross-XCD writeback churn.
// Edge stream is re-scanned 8x but passes 2-8 are L3-resident (12.8 MB << 256 MB).

static __global__ void k_scatter3(const int* __restrict__ src, const int* __restrict__ dst,
                                  const int* __restrict__ typ, const int* __restrict__ hop,
                                  int* __restrict__ cursor, unsigned int* __restrict__ src_s) {
    const int slice = blockIdx.x >> 3;
    const int range = blockIdx.x & 7;
    const int lo = range * (NN / 8);       // 6250-node ranges (50000 % 8 == 0)
    const int hi = lo + (NN / 8);
    const int base = slice * SC_CHUNK + threadIdx.x;
#pragma unroll
    for (int k = 0; k < SC_CHUNK / 256; ++k) {
        int e = base + k * 256;
        if (e < NE) {
            int d = dst[e];
            if (d >= lo && d < hi) {
                int slot = atomicAdd(&cursor[d * NBKT + typ[e]], 1);
                src_s[slot] = (unsigned int)src[e] | ((unsigned int)hop[e] << 16);
            }
        }
    }
}

// ---------------- f32 -> bf16 plane convert (initial x only) ----------------

static __global__ void k_cvt(const float* __restrict__ in, unsigned short* __restrict__ out) {
    int i = blockIdx.x * blockDim.x + threadIdx.x;   // one float4 per thread
    if (i >= NN * DIM / 4) return;
    float4 v = ((const float4*)in)[i];
    uint2 p;
    p.x = bf16rne(v.x) | (bf16rne(v.y) << 16);
    p.y = bf16rne(v.z) | (bf16rne(v.w) << 16);
    ((uint2*)out)[i] = p;
}

// ---------------- W pre-pack, interleaved k-map: k = 4*dd + m --------------------------
// Bpack[((T*4+nt)*8+ks)*512 + lane*8 + j] = Wcat_T[k = ks*32+8*(lane>>4)+j][nt*16+lane&15]
// with Wcat row k -> matrix m = k&3, row dd = k>>2. A-side uses the same labeling.

static __global__ void k_pack(const float* __restrict__ W_edge, const float* __restrict__ W_t,
                              unsigned short* __restrict__ Bpack) {
    int idx = blockIdx.x * 256 + threadIdx.x;   // 65536 total
    if (idx >= 4 * 4 * 8 * 512) return;
    int j = idx & 7;
    int lane = (idx >> 3) & 63;
    int ks = (idx >> 9) & 7;
    int nt = (idx >> 12) & 3;
    int T = idx >> 14;
    int k = ks * 32 + 8 * (lane >> 4) + j;     // k within [0,256)
    int n = nt * 16 + (lane & 15);
    int m = k & 3, dd = k >> 2;
    float v;
    if (m < 3) v = W_edge[(((size_t)m * TL + T) * DIM + dd) * DIM + n];
    else if (T >= 1) v = W_t[((size_t)T * DIM + dd) * DIM + n];
    else v = 0.f;                               // T=0: hop slice contributes zero
    Bpack[idx] = (unsigned short)bf16rne(v);
}

// ---------------- Aggregation: one wave per node; per-bucket sub-loops; packed A store ---

template <int T>
static __global__ __launch_bounds__(256) void k_agg(
        const int* __restrict__ rs, const unsigned int* __restrict__ src_s,
        const unsigned short* __restrict__ xb,
        const float* __restrict__ nu_edge, const float* __restrict__ nu_kt,
        const unsigned short* __restrict__ gp2, const unsigned short* __restrict__ gp3,
        const unsigned short* __restrict__ gp4,
        unsigned short* __restrict__ aAll, unsigned short* __restrict__ g2,
        unsigned short* __restrict__ g3, unsigned short* __restrict__ g4) {
    int g = blockIdx.x * blockDim.x + threadIdx.x;
    int node = g >> 6;
    if (node >= NN) return;
    int lane = g & 63;
    const size_t po = (size_t)node * DIM + lane;

    // hop A-row for this layer's matmul: coalesced bf16 loads, independent of gather loop
    float hp = 0.f;
    if (T >= 1) {
        hp = nu_kt[T * MH + 2] * bf2f(gp2[po]);
        if (T >= 2) hp = fmaf(nu_kt[T * MH + 3], bf2f(gp3[po]), hp);
        if (T >= 3) hp = fmaf(nu_kt[T * MH + 4], bf2f(gp4[po]), hp);
    }

    int ro = 0;
    if (lane < 4) ro = rs[node * NBKT + lane];
    const int b0 = __builtin_amdgcn_readlane(ro, 0);
    const int b1 = __builtin_amdgcn_readlane(ro, 1);
    const int b2 = __builtin_amdgcn_readlane(ro, 2);
    const int b3 = __builtin_amdgcn_readlane(ro, 3);
    const int nt = b3 - b0, t1 = b1 - b0, t2 = b2 - b0;

    float s0 = 0.f, s1 = 0.f, s2 = 0.f;
    float h2 = 0.f, h3 = 0.f, h4 = 0.f;

#define EDGE_BODY(SPEXPR, ACC)                                                   \
    {                                                                            \
        unsigned int sp = (SPEXPR);                                              \
        int srcn = (int)(sp & 0xFFFFu);                                          \
        float v = bf2f(xb[(size_t)srcn * DIM + lane]);                           \
        ACC += v;                                                                \
        if (T <= 2) {                                                            \
            int hop = (int)(sp >> 16);                                           \
            h2 = fmaf((hop == 2) ? 1.f : 0.f, v, h2);                            \
            if (T <= 1) h3 = fmaf((hop == 3) ? 1.f : 0.f, v, h3);                \
            if (T == 0) h4 = fmaf((hop == 4) ? 1.f : 0.f, v, h4);                \
        }                                                                        \
    }

    if (nt <= 64) {
        int sv = (lane < nt) ? (int)src_s[b0 + lane] : 0;
#pragma unroll 8
        for (int i = 0; i < t1; ++i)
            EDGE_BODY((unsigned int)__builtin_amdgcn_readlane(sv, i), s0)
#pragma unroll 8
        for (int i = t1; i < t2; ++i)
            EDGE_BODY((unsigned int)__builtin_amdgcn_readlane(sv, i), s1)
#pragma unroll 8
        for (int i = t2; i < nt; ++i)
            EDGE_BODY((unsigned int)__builtin_amdgcn_readlane(sv, i), s2)
    } else {
#pragma unroll 4
        for (int i = 0; i < t1; ++i) EDGE_BODY(src_s[b0 + i], s0)
#pragma unroll 4
        for (int i = t1; i < t2; ++i) EDGE_BODY(src_s[b0 + i], s1)
#pragma unroll 4
        for (int i = t2; i < nt; ++i) EDGE_BODY(src_s[b0 + i], s2)
    }
#undef EDGE_BODY

    float nu0 = nu_edge[0 * TL + T], nu1 = nu_edge[1 * TL + T], nu2 = nu_edge[2 * TL + T];
    // packed A row: [node][d*4 + m], lane=d -> one uint2 store
    uint2 pk;
    pk.x = bf16rne(nu0 * s0) | (bf16rne(nu1 * s1) << 16);
    pk.y = bf16rne(nu2 * s2) | (bf16rne(hp) << 16);
    *(uint2*)(aAll + (size_t)node * 256 + lane * 4) = pk;
    if (T <= 2) g2[po] = (unsigned short)bf16rne(h2);
    if (T <= 1) g3[po] = (unsigned short)bf16rne(h3);
    if (T == 0) g4[po] = (unsigned short)bf16rne(h4);
}

// ---------------- Matmul via MFMA: A[50048x256]bf16 @ B[256x64]bf16, fused epilogue ------

template <int T>
static __global__ __launch_bounds__(256) void k_mm(
        const unsigned short* __restrict__ aAll,
        const unsigned short* __restrict__ Bpack,
        const float* __restrict__ b_edge, const float* __restrict__ nu_edge,
        const float* __restrict__ b_t, const float* __restrict__ nu_kt,
        const float* __restrict__ xin, float* __restrict__ xout,
        unsigned short* __restrict__ xbo) {
    const int w = __builtin_amdgcn_readfirstlane(threadIdx.x >> 6);
    const int l = threadIdx.x & 63;
    const int g = l >> 4, i = l & 15;
    const int m0 = blockIdx.x * 64 + w * 16;

    const float nu0 = nu_edge[0 * TL + T], nu1 = nu_edge[1 * TL + T],
                nu2 = nu_edge[2 * TL + T];
    float nsum = 0.f;
    if (T >= 1) {
        nsum = nu_kt[T * MH + 2];
        if (T >= 2) nsum += nu_kt[T * MH + 3];
        if (T >= 3) nsum += nu_kt[T * MH + 4];
    }

    f32x4 acc[4];
#pragma unroll
    for (int nt = 0; nt < 4; ++nt) {
        int col = nt * 16 + i;
        float b = nu0 * b_edge[(0 * TL + T) * DIM + col]
                + nu1 * b_edge[(1 * TL + T) * DIM + col]
                + nu2 * b_edge[(2 * TL + T) * DIM + col];
        if (T >= 1) b = fmaf(nsum, b_t[T * DIM + col], b);
        acc[nt] = (f32x4){b, b, b, b};
    }

    // A: row = m0+i, k = ks*32 + 8g + [0..8)  -> one uint4 per k-step
    const uint4* __restrict__ Abase = (const uint4*)(aAll + (size_t)(m0 + i) * 256 + g * 8);
    const uint4* __restrict__ Bu = (const uint4*)Bpack;

#pragma unroll
    for (int ks = 0; ks < 8; ++ks) {
        short8 a = __builtin_bit_cast(short8, Abase[ks * 4]);
#pragma unroll
        for (int nt = 0; nt < 4; ++nt) {
            short8 b = __builtin_bit_cast(short8, Bu[(((size_t)T * 4 + nt) * 8 + ks) * 64 + l]);
            acc[nt] = __builtin_amdgcn_mfma_f32_16x16x32_bf16(a, b, acc[nt], 0, 0, 0);
        }
    }

    // D: row = m0 + 4g + r, col = nt*16 + i  (m89-verified mapping)
#pragma unroll
    for (int nt = 0; nt < 4; ++nt) {
        int col = nt * 16 + i;
#pragma unroll
        for (int r = 0; r < 4; ++r) {
            int node = m0 + 4 * g + r;
            if (node < NN) {
                size_t idx = (size_t)node * DIM + col;
                float v = acc[nt][r];
                v = v > 0.f ? v : 0.f;
                float o = xin[idx] + v;
                xout[idx] = o;
                if (xbo) xbo[idx] = (unsigned short)bf16rne(o);
            }
        }
    }
}

// ---------------- Host ----------------

extern "C" void kernel_launch(void* const* d_in, const int* in_sizes, int n_in,
                              void* d_out, int out_size, void* d_ws, size_t ws_size,
                              hipStream_t stream) {
    const float* x       = (const float*)d_in[0];
    const float* W_edge  = (const float*)d_in[1];
    const float* b_edge  = (const float*)d_in[2];
    const float* nu_edge = (const float*)d_in[3];
    const float* W_t     = (const float*)d_in[4];
    const float* b_t     = (const float*)d_in[5];
    const float* nu_kt   = (const float*)d_in[6];
    const int* esrc = (const int*)d_in[7];
    const int* edst = (const int*)d_in[8];
    const int* ehop = (const int*)d_in[9];
    const int* etyp = (const int*)d_in[10];
    float* out = (float*)d_out;

    char* ws = (char*)d_ws;
    size_t off = 0;
    auto alloc = [&](size_t bytes) {
        void* p = ws + off;
        off = (off + bytes + 255) & ~(size_t)255;
        return p;
    };
    const size_t PL  = (size_t)NN * DIM * 4;         // f32 feature plane
    const size_t PLB = (size_t)NN * DIM * 2;         // bf16 feature plane
    int* counts = (int*)alloc((size_t)NB * 4);
    int* rs     = (int*)alloc(((size_t)NB + 1) * 4);
    int* cursor = (int*)alloc((size_t)NB * 4);
    int* bsum   = (int*)alloc(1024 * 4);
    int* bexcl  = (int*)alloc(1024 * 4);
    unsigned int* src_s = (unsigned int*)alloc((size_t)NE * 4);
    float* hA   = (float*)alloc(PL);                 // ping-pong layer outputs (f32)
    float* hB   = (float*)alloc(PL);
    unsigned short* xb0 = (unsigned short*)alloc(PLB);   // bf16 shadows
    unsigned short* hAb = (unsigned short*)alloc(PLB);
    unsigned short* hBb = (unsigned short*)alloc(PLB);
    unsigned short* aAll  = (unsigned short*)alloc((size_t)NN_PAD * 256 * 2);  // [node][256] bf16
    unsigned short* Bpack = (unsigned short*)alloc((size_t)4 * 4 * 8 * 512 * 2);
    unsigned short* G2A  = (unsigned short*)alloc(PLB);  // rolling hop-sum planes (bf16)
    unsigned short* G2B  = (unsigned short*)alloc(PLB);
    unsigned short* G3A  = (unsigned short*)alloc(PLB);
    unsigned short* G3B  = (unsigned short*)alloc(PLB);
    unsigned short* G4   = (unsigned short*)alloc(PLB);
    (void)ws_size; (void)in_sizes; (void)n_in; (void)out_size;

    // CSR build (graph static across layers) + bf16 converts + W pre-pack
    hipMemsetAsync(counts, 0, (size_t)NB * 4, stream);
    k_hist3<<<(NE + 255) / 256, 256, 0, stream>>>(edst, etyp, counts);
    k_cvt<<<(NN * DIM / 4 + 255) / 256, 256, 0, stream>>>(x, xb0);
    k_pack<<<256, 256, 0, stream>>>(W_edge, W_t, Bpack);
    k_scanA<<<SCAN_BLK, 1024, 0, stream>>>(counts, rs, bsum);
    k_scanB<<<1, 512, 0, stream>>>(bsum, bexcl, rs);
    k_scanC<<<SCAN_BLK, 1024, 0, stream>>>(rs, cursor, bexcl);
    k_scatter3<<<SC_SLICES * 8, 256, 0, stream>>>(esrc, edst, etyp, ehop, cursor, src_s);

    const int ga = (NN * DIM + 255) / 256;   // one wave per node
    const int gm = NN_PAD / 64;              // 782 blocks, 64-node tile, 256 thr

    // t = 0: write G2[0],G3[0],G4[0]; no hop row (B hop slice = 0)
    k_agg<0><<<ga, 256, 0, stream>>>(rs, src_s, xb0, nu_edge, nu_kt,
                                     G4, G4, G4, aAll, G2A, G3A, G4);
    k_mm<0><<<gm, 256, 0, stream>>>(aAll, Bpack, b_edge, nu_edge, b_t, nu_kt,
                                    x, hA, hAb);
    // t = 1: write G2[1],G3[1]; hop row = nk2*G2[0]
    k_agg<1><<<ga, 256, 0, stream>>>(rs, src_s, hAb, nu_edge, nu_kt,
                                     G2A, G4, G4, aAll, G2B, G3B, G4);
    k_mm<1><<<gm, 256, 0, stream>>>(aAll, Bpack, b_edge, nu_edge, b_t, nu_kt,
                                    hA, hB, hBb);
    // t = 2: write G2[2] (->G2A, layer-0 content consumed at t=1);
    //        hop row = nk2*G2[1] + nk3*G3[0]
    k_agg<2><<<ga, 256, 0, stream>>>(rs, src_s, hBb, nu_edge, nu_kt,
                                     G2B, G3A, G4, aAll, G2A, G3A, G4);
    k_mm<2><<<gm, 256, 0, stream>>>(aAll, Bpack, b_edge, nu_edge, b_t, nu_kt,
                                    hB, hA, hAb);
    // t = 3: no G writes; hop row = nk2*G2[2] + nk3*G3[1] + nk4*G4[0]
    k_agg<3><<<ga, 256, 0, stream>>>(rs, src_s, hAb, nu_edge, nu_kt,
                                     G2A, G3B, G4, aAll, G2B, G3B, G4);
    k_mm<3><<<gm, 256, 0, stream>>>(aAll, Bpack, b_edge, nu_edge, b_t, nu_kt,
                                    hA, out, (unsigned short*)nullptr);
}

// Round 16
// 313.685 us; speedup vs baseline: 2.0153x; 1.1658x over previous
//
#include <hip/hip_runtime.h>

#define NN 50000
#define NN_PAD 50048                    // 64-aligned, covers last k_mm tile
#define NE 800000
#define DIM 64
#define TL 4
#define ET 3
#define MH 6
#define NBKT 3
#define NB (NN * NBKT)                  // 150000
#define SCAN_BLK ((NB + 1023) / 1024)   // 147
#define SC_CHUNK 2048                   // edges per scatter slice
#define SC_SLICES ((NE + SC_CHUNK - 1) / SC_CHUNK)   // 391

typedef __attribute__((ext_vector_type(8))) short short8;
typedef __attribute__((ext_vector_type(4))) float f32x4;

__device__ __forceinline__ unsigned bf16rne(float f) {
    unsigned b = __float_as_uint(f);
    return (b + 0x7FFFu + ((b >> 16) & 1u)) >> 16;
}
__device__ __forceinline__ float bf2f_lo(unsigned u) {       // low bf16 of a dword
    return __uint_as_float(u << 16);
}
__device__ __forceinline__ float bf2f_hi(unsigned u) {       // high bf16 of a dword
    return __uint_as_float(u & 0xFFFF0000u);
}

// ---------------- CSR build: 3 type buckets per node, hop packed in entry ----------------

static __global__ void k_hist3(const int* __restrict__ dst, const int* __restrict__ typ,
                               int* __restrict__ counts) {
    int e = blockIdx.x * blockDim.x + threadIdx.x;
    if (e >= NE) return;
    atomicAdd(&counts[dst[e] * NBKT + typ[e]], 1);
}

static __global__ void k_scanA(const int* __restrict__ counts, int* __restrict__ rs,
                               int* __restrict__ bsum) {
    __shared__ int sm[1024];
    int idx = blockIdx.x * 1024 + threadIdx.x;
    int v = (idx < NB) ? counts[idx] : 0;
    sm[threadIdx.x] = v;
    __syncthreads();
    for (int off = 1; off < 1024; off <<= 1) {
        int t = (threadIdx.x >= off) ? sm[threadIdx.x - off] : 0;
        __syncthreads();
        sm[threadIdx.x] += t;
        __syncthreads();
    }
    if (idx < NB) rs[idx] = sm[threadIdx.x] - v;   // exclusive within block
    if (threadIdx.x == 1023) bsum[blockIdx.x] = sm[1023];
}

static __global__ void k_scanB(const int* __restrict__ bsum, int* __restrict__ bexcl,
                               int* __restrict__ rs) {
    __shared__ int sm[512];
    int tid = threadIdx.x;
    int v = (tid < SCAN_BLK) ? bsum[tid] : 0;
    sm[tid] = v;
    __syncthreads();
    for (int off = 1; off < 512; off <<= 1) {
        int t = (tid >= off) ? sm[tid - off] : 0;
        __syncthreads();
        sm[tid] += t;
        __syncthreads();
    }
    if (tid < SCAN_BLK) bexcl[tid] = sm[tid] - v;
    if (tid == 511) rs[NB] = sm[511];              // grand total
}

static __global__ void k_scanC(int* __restrict__ rs, int* __restrict__ cursor,
                               const int* __restrict__ bexcl) {
    int idx = blockIdx.x * 1024 + threadIdx.x;
    if (idx >= NB) return;
    int r = rs[idx] + bexcl[blockIdx.x];
    rs[idx] = r;
    cursor[idx] = r;
}

// XCD-affine scatter (R15-proven): each src_s / cursor line written by one XCD only.

static __global__ void k_scatter3(const int* __restrict__ src, const int* __restrict__ dst,
                                  const int* __restrict__ typ, const int* __restrict__ hop,
                                  int* __restrict__ cursor, unsigned int* __restrict__ src_s) {
    const int slice = blockIdx.x >> 3;
    const int range = blockIdx.x & 7;
    const int lo = range * (NN / 8);
    const int hi = lo + (NN / 8);
    const int base = slice * SC_CHUNK + threadIdx.x;
#pragma unroll
    for (int k = 0; k < SC_CHUNK / 256; ++k) {
        int e = base + k * 256;
        if (e < NE) {
            int d = dst[e];
            if (d >= lo && d < hi) {
                int slot = atomicAdd(&cursor[d * NBKT + typ[e]], 1);
                src_s[slot] = (unsigned int)src[e] | ((unsigned int)hop[e] << 16);
            }
        }
    }
}

// ---------------- f32 -> bf16 plane convert (initial x only) ----------------

static __global__ void k_cvt(const float* __restrict__ in, unsigned short* __restrict__ out) {
    int i = blockIdx.x * blockDim.x + threadIdx.x;   // one float4 per thread
    if (i >= NN * DIM / 4) return;
    float4 v = ((const float4*)in)[i];
    uint2 p;
    p.x = bf16rne(v.x) | (bf16rne(v.y) << 16);
    p.y = bf16rne(v.z) | (bf16rne(v.w) << 16);
    ((uint2*)out)[i] = p;
}

// ---------------- W pre-pack, interleaved k-map: k = 4*dd + m --------------------------

static __global__ void k_pack(const float* __restrict__ W_edge, const float* __restrict__ W_t,
                              unsigned short* __restrict__ Bpack) {
    int idx = blockIdx.x * 256 + threadIdx.x;   // 65536 total
    if (idx >= 4 * 4 * 8 * 512) return;
    int j = idx & 7;
    int lane = (idx >> 3) & 63;
    int ks = (idx >> 9) & 7;
    int nt = (idx >> 12) & 3;
    int T = idx >> 14;
    int k = ks * 32 + 8 * (lane >> 4) + j;     // k within [0,256)
    int n = nt * 16 + (lane & 15);
    int m = k & 3, dd = k >> 2;
    float v;
    if (m < 3) v = W_edge[(((size_t)m * TL + T) * DIM + dd) * DIM + n];
    else if (T >= 1) v = W_t[((size_t)T * DIM + dd) * DIM + n];
    else v = 0.f;                               // T=0: hop slice contributes zero
    Bpack[idx] = (unsigned short)bf16rne(v);
}

// ---------------- Aggregation: pair-gather (2 edges per load), merged predicated loop ----
// Lanes 0-31 take edge 2p (dims 2hl,2hl+1), lanes 32-63 take edge 2p+1.
// shfl_xor(32) combines halves at the end; lanes<32 store packed A (uint4) + G (uint).

template <int T>
static __global__ __launch_bounds__(256) void k_agg(
        const int* __restrict__ rs, const unsigned int* __restrict__ src_s,
        const unsigned short* __restrict__ xb,
        const float* __restrict__ nu_edge, const float* __restrict__ nu_kt,
        const unsigned short* __restrict__ gp2, const unsigned short* __restrict__ gp3,
        const unsigned short* __restrict__ gp4,
        unsigned short* __restrict__ aAll, unsigned short* __restrict__ g2,
        unsigned short* __restrict__ g3, unsigned short* __restrict__ g4) {
    int g = blockIdx.x * blockDim.x + threadIdx.x;
    int node = g >> 6;
    if (node >= NN) return;
    int lane = g & 63;
    const int half = lane >> 5;          // 0: edge 2p, 1: edge 2p+1
    const int hl = lane & 31;            // owns dims 2hl, 2hl+1

    // hop A-row prologue (pair layout, lanes<32): independent coalesced loads
    float hplo = 0.f, hphi = 0.f;
    if (T >= 1 && lane < 32) {
        const float nk2 = nu_kt[T * MH + 2];
        unsigned p2 = *(const unsigned*)(gp2 + (size_t)node * DIM + 2 * hl);
        hplo = nk2 * bf2f_lo(p2);
        hphi = nk2 * bf2f_hi(p2);
        if (T >= 2) {
            const float nk3 = nu_kt[T * MH + 3];
            unsigned p3 = *(const unsigned*)(gp3 + (size_t)node * DIM + 2 * hl);
            hplo = fmaf(nk3, bf2f_lo(p3), hplo);
            hphi = fmaf(nk3, bf2f_hi(p3), hphi);
        }
        if (T >= 3) {
            const float nk4 = nu_kt[T * MH + 4];
            unsigned p4 = *(const unsigned*)(gp4 + (size_t)node * DIM + 2 * hl);
            hplo = fmaf(nk4, bf2f_lo(p4), hplo);
            hphi = fmaf(nk4, bf2f_hi(p4), hphi);
        }
    }

    int ro = 0;
    if (lane < 4) ro = rs[node * NBKT + lane];
    const int b0 = __builtin_amdgcn_readlane(ro, 0);
    const int b1 = __builtin_amdgcn_readlane(ro, 1);
    const int b2 = __builtin_amdgcn_readlane(ro, 2);
    const int b3 = __builtin_amdgcn_readlane(ro, 3);
    const int nt = b3 - b0, t1 = b1 - b0, t2 = b2 - b0;
    const int np = (nt + 1) >> 1;

    float s0l = 0.f, s0h = 0.f, s1l = 0.f, s1h = 0.f, s2l = 0.f, s2h = 0.f;
    float h2l = 0.f, h2h = 0.f, h3l = 0.f, h3h = 0.f, h4l = 0.f, h4h = 0.f;

#define PAIR_BODY(SPA, SPB)                                                      \
    {                                                                            \
        unsigned sp = half ? (SPB) : (SPA);                                      \
        int idx = 2 * p + half;                                                  \
        int srcn = (int)(sp & 0xFFFFu);                                          \
        unsigned pk = *(const unsigned*)(xb + (size_t)srcn * DIM + 2 * hl);      \
        float vl = bf2f_lo(pk), vh = bf2f_hi(pk);                                \
        float f0 = (idx < t1) ? 1.f : 0.f;                                       \
        float f1 = (idx >= t1 && idx < t2) ? 1.f : 0.f;                          \
        float f2 = (idx >= t2 && idx < nt) ? 1.f : 0.f;                          \
        s0l = fmaf(f0, vl, s0l); s0h = fmaf(f0, vh, s0h);                        \
        s1l = fmaf(f1, vl, s1l); s1h = fmaf(f1, vh, s1h);                        \
        s2l = fmaf(f2, vl, s2l); s2h = fmaf(f2, vh, s2h);                        \
        if (T <= 2) {                                                            \
            int hop = (int)(sp >> 16);                                           \
            float g2f = (hop == 2) ? 1.f : 0.f;                                  \
            h2l = fmaf(g2f, vl, h2l); h2h = fmaf(g2f, vh, h2h);                  \
            if (T <= 1) {                                                        \
                float g3f = (hop == 3) ? 1.f : 0.f;                              \
                h3l = fmaf(g3f, vl, h3l); h3h = fmaf(g3f, vh, h3h);              \
            }                                                                    \
            if (T == 0) {                                                        \
                float g4f = (hop == 4) ? 1.f : 0.f;                              \
                h4l = fmaf(g4f, vl, h4l); h4h = fmaf(g4f, vh, h4h);              \
            }                                                                    \
        }                                                                        \
    }

    if (nt <= 64) {
        int sv = (lane < nt) ? (int)src_s[b0 + lane] : 0;   // padded: hop=0, srcn=0
#pragma unroll 8
        for (int p = 0; p < np; ++p) {
            unsigned spA = (unsigned)__builtin_amdgcn_readlane(sv, 2 * p);
            unsigned spB = (unsigned)__builtin_amdgcn_readlane(sv, 2 * p + 1);
            PAIR_BODY(spA, spB)
        }
    } else {
#pragma unroll 4
        for (int p = 0; p < np; ++p) {
            int idx0 = 2 * p + half;
            unsigned sp0 = (idx0 < nt) ? src_s[b0 + idx0] : 0u;
            PAIR_BODY(sp0, sp0)
        }
    }
#undef PAIR_BODY

    // combine halves: lane l += lane l^32
    s0l += __shfl_xor(s0l, 32); s0h += __shfl_xor(s0h, 32);
    s1l += __shfl_xor(s1l, 32); s1h += __shfl_xor(s1h, 32);
    s2l += __shfl_xor(s2l, 32); s2h += __shfl_xor(s2h, 32);
    if (T <= 2) { h2l += __shfl_xor(h2l, 32); h2h += __shfl_xor(h2h, 32); }
    if (T <= 1) { h3l += __shfl_xor(h3l, 32); h3h += __shfl_xor(h3h, 32); }
    if (T == 0) { h4l += __shfl_xor(h4l, 32); h4h += __shfl_xor(h4h, 32); }

    if (lane < 32) {
        float nu0 = nu_edge[0 * TL + T], nu1 = nu_edge[1 * TL + T], nu2 = nu_edge[2 * TL + T];
        uint4 pk;   // packed A row [node][d*4+m] for d = 2hl, 2hl+1
        pk.x = bf16rne(nu0 * s0l) | (bf16rne(nu1 * s1l) << 16);
        pk.y = bf16rne(nu2 * s2l) | (bf16rne(hplo) << 16);
        pk.z = bf16rne(nu0 * s0h) | (bf16rne(nu1 * s1h) << 16);
        pk.w = bf16rne(nu2 * s2h) | (bf16rne(hphi) << 16);
        *(uint4*)(aAll + (size_t)node * 256 + hl * 8) = pk;
        const size_t go = (size_t)node * DIM + 2 * hl;
        if (T <= 2) *(unsigned*)(g2 + go) = bf16rne(h2l) | (bf16rne(h2h) << 16);
        if (T <= 1) *(unsigned*)(g3 + go) = bf16rne(h3l) | (bf16rne(h3h) << 16);
        if (T == 0) *(unsigned*)(g4 + go) = bf16rne(h4l) | (bf16rne(h4h) << 16);
    }
}

// ---------------- Matmul via MFMA: A[50048x256]bf16 @ B[256x64]bf16, fused epilogue ------

template <int T>
static __global__ __launch_bounds__(256) void k_mm(
        const unsigned short* __restrict__ aAll,
        const unsigned short* __restrict__ Bpack,
        const float* __restrict__ b_edge, const float* __restrict__ nu_edge,
        const float* __restrict__ b_t, const float* __restrict__ nu_kt,
        const float* __restrict__ xin, float* __restrict__ xout,
        unsigned short* __restrict__ xbo) {
    const int w = __builtin_amdgcn_readfirstlane(threadIdx.x >> 6);
    const int l = threadIdx.x & 63;
    const int g = l >> 4, i = l & 15;
    const int m0 = blockIdx.x * 64 + w * 16;

    const float nu0 = nu_edge[0 * TL + T], nu1 = nu_edge[1 * TL + T],
                nu2 = nu_edge[2 * TL + T];
    float nsum = 0.f;
    if (T >= 1) {
        nsum = nu_kt[T * MH + 2];
        if (T >= 2) nsum += nu_kt[T * MH + 3];
        if (T >= 3) nsum += nu_kt[T * MH + 4];
    }

    f32x4 acc[4];
#pragma unroll
    for (int nt = 0; nt < 4; ++nt) {
        int col = nt * 16 + i;
        float b = nu0 * b_edge[(0 * TL + T) * DIM + col]
                + nu1 * b_edge[(1 * TL + T) * DIM + col]
                + nu2 * b_edge[(2 * TL + T) * DIM + col];
        if (T >= 1) b = fmaf(nsum, b_t[T * DIM + col], b);
        acc[nt] = (f32x4){b, b, b, b};
    }

    // A: row = m0+i, k = ks*32 + 8g + [0..8)  -> one uint4 per k-step
    const uint4* __restrict__ Abase = (const uint4*)(aAll + (size_t)(m0 + i) * 256 + g * 8);
    const uint4* __restrict__ Bu = (const uint4*)Bpack;

#pragma unroll
    for (int ks = 0; ks < 8; ++ks) {
        short8 a = __builtin_bit_cast(short8, Abase[ks * 4]);
#pragma unroll
        for (int nt = 0; nt < 4; ++nt) {
            short8 b = __builtin_bit_cast(short8, Bu[(((size_t)T * 4 + nt) * 8 + ks) * 64 + l]);
            acc[nt] = __builtin_amdgcn_mfma_f32_16x16x32_bf16(a, b, acc[nt], 0, 0, 0);
        }
    }

    // D: row = m0 + 4g + r, col = nt*16 + i  (m89-verified mapping)
#pragma unroll
    for (int nt = 0; nt < 4; ++nt) {
        int col = nt * 16 + i;
#pragma unroll
        for (int r = 0; r < 4; ++r) {
            int node = m0 + 4 * g + r;
            if (node < NN) {
                size_t idx = (size_t)node * DIM + col;
                float v = acc[nt][r];
                v = v > 0.f ? v : 0.f;
                float o = xin[idx] + v;
                xout[idx] = o;
                if (xbo) xbo[idx] = (unsigned short)bf16rne(o);
            }
        }
    }
}

// ---------------- Host ----------------

extern "C" void kernel_launch(void* const* d_in, const int* in_sizes, int n_in,
                              void* d_out, int out_size, void* d_ws, size_t ws_size,
                              hipStream_t stream) {
    const float* x       = (const float*)d_in[0];
    const float* W_edge  = (const float*)d_in[1];
    const float* b_edge  = (const float*)d_in[2];
    const float* nu_edge = (const float*)d_in[3];
    const float* W_t     = (const float*)d_in[4];
    const float* b_t     = (const float*)d_in[5];
    const float* nu_kt   = (const float*)d_in[6];
    const int* esrc = (const int*)d_in[7];
    const int* edst = (const int*)d_in[8];
    const int* ehop = (const int*)d_in[9];
    const int* etyp = (const int*)d_in[10];
    float* out = (float*)d_out;

    char* ws = (char*)d_ws;
    size_t off = 0;
    auto alloc = [&](size_t bytes) {
        void* p = ws + off;
        off = (off + bytes + 255) & ~(size_t)255;
        return p;
    };
    const size_t PL  = (size_t)NN * DIM * 4;         // f32 feature plane
    const size_t PLB = (size_t)NN * DIM * 2;         // bf16 feature plane
    int* counts = (int*)alloc((size_t)NB * 4);
    int* rs     = (int*)alloc(((size_t)NB + 1) * 4);
    int* cursor = (int*)alloc((size_t)NB * 4);
    int* bsum   = (int*)alloc(1024 * 4);
    int* bexcl  = (int*)alloc(1024 * 4);
    unsigned int* src_s = (unsigned int*)alloc((size_t)NE * 4);
    float* hA   = (float*)alloc(PL);                 // ping-pong layer outputs (f32)
    float* hB   = (float*)alloc(PL);
    unsigned short* xb0 = (unsigned short*)alloc(PLB);   // bf16 shadows
    unsigned short* hAb = (unsigned short*)alloc(PLB);
    unsigned short* hBb = (unsigned short*)alloc(PLB);
    unsigned short* aAll  = (unsigned short*)alloc((size_t)NN_PAD * 256 * 2);  // [node][256] bf16
    unsigned short* Bpack = (unsigned short*)alloc((size_t)4 * 4 * 8 * 512 * 2);
    unsigned short* G2A  = (unsigned short*)alloc(PLB);  // rolling hop-sum planes (bf16)
    unsigned short* G2B  = (unsigned short*)alloc(PLB);
    unsigned short* G3A  = (unsigned short*)alloc(PLB);
    unsigned short* G3B  = (unsigned short*)alloc(PLB);
    unsigned short* G4   = (unsigned short*)alloc(PLB);
    (void)ws_size; (void)in_sizes; (void)n_in; (void)out_size;

    // CSR build (graph static across layers) + bf16 converts + W pre-pack
    hipMemsetAsync(counts, 0, (size_t)NB * 4, stream);
    k_hist3<<<(NE + 255) / 256, 256, 0, stream>>>(edst, etyp, counts);
    k_cvt<<<(NN * DIM / 4 + 255) / 256, 256, 0, stream>>>(x, xb0);
    k_pack<<<256, 256, 0, stream>>>(W_edge, W_t, Bpack);
    k_scanA<<<SCAN_BLK, 1024, 0, stream>>>(counts, rs, bsum);
    k_scanB<<<1, 512, 0, stream>>>(bsum, bexcl, rs);
    k_scanC<<<SCAN_BLK, 1024, 0, stream>>>(rs, cursor, bexcl);
    k_scatter3<<<SC_SLICES * 8, 256, 0, stream>>>(esrc, edst, etyp, ehop, cursor, src_s);

    const int ga = (NN * DIM + 255) / 256;   // one wave per node
    const int gm = NN_PAD / 64;              // 782 blocks, 64-node tile, 256 thr

    // t = 0: write G2[0],G3[0],G4[0]; no hop row (B hop slice = 0)
    k_agg<0><<<ga, 256, 0, stream>>>(rs, src_s, xb0, nu_edge, nu_kt,
                                     G4, G4, G4, aAll, G2A, G3A, G4);
    k_mm<0><<<gm, 256, 0, stream>>>(aAll, Bpack, b_edge, nu_edge, b_t, nu_kt,
                                    x, hA, hAb);
    // t = 1: write G2[1],G3[1]; hop row = nk2*G2[0]
    k_agg<1><<<ga, 256, 0, stream>>>(rs, src_s, hAb, nu_edge, nu_kt,
                                     G2A, G4, G4, aAll, G2B, G3B, G4);
    k_mm<1><<<gm, 256, 0, stream>>>(aAll, Bpack, b_edge, nu_edge, b_t, nu_kt,
                                    hA, hB, hBb);
    // t = 2: write G2[2] (->G2A, layer-0 content consumed at t=1);
    //        hop row = nk2*G2[1] + nk3*G3[0]
    k_agg<2><<<ga, 256, 0, stream>>>(rs, src_s, hBb, nu_edge, nu_kt,
                                     G2B, G3A, G4, aAll, G2A, G3A, G4);
    k_mm<2><<<gm, 256, 0, stream>>>(aAll, Bpack, b_edge, nu_edge, b_t, nu_kt,
                                    hB, hA, hAb);
    // t = 3: no G writes; hop row = nk2*G2[2] + nk3*G3[1] + nk4*G4[0]
    k_agg<3><<<ga, 256, 0, stream>>>(rs, src_s, hAb, nu_edge, nu_kt,
                                     G2A, G3B, G4, aAll, G2B, G3B, G4);
    k_mm<3><<<gm, 256, 0, stream>>>(aAll, Bpack, b_edge, nu_edge, b_t, nu_kt,
                                    hA, out, (unsigned short*)nullptr);
}